// Round 3
// baseline (1261.783 us; speedup 1.0000x reference)
//
#include <hip/hip_runtime.h>

typedef unsigned short u16;
typedef __attribute__((ext_vector_type(8))) short s16x8;
typedef __attribute__((ext_vector_type(8))) __bf16 bf16x8;
typedef __attribute__((ext_vector_type(8))) unsigned short u16x8;
typedef __attribute__((ext_vector_type(4))) float f32x4;

#define BN_EPS 1e-5f

// ---------- static device buffers: avoid d_ws entirely (ws_size unknown; suspected OOB
// in rounds 0/1). ~187 MiB .bss, allocated at module load, rewritten every call. ----------
__device__ u16   g_Z[(size_t)65536 * 1024];      // 128 MiB GEMM-a output (l0 uses stride 512)
__device__ float g_pooled[(size_t)8192 * 1024];  // 32 MiB pooled pre-BN
__device__ float g_h2pre[8192 * 256];            // 8 MiB
__device__ u16   g_h2b[8192 * 256];              // 4 MiB feat0 bf16
__device__ u16   g_hl0b[8192 * 512];             // 8 MiB feat1 bf16
__device__ float g_y1[8192 * 64];                // 2 MiB
__device__ u16   g_wm0a[512 * 512];              // [W1 | W2-W1] bf16
__device__ u16   g_w0b[512 * 512];
__device__ u16   g_wm1a[1024 * 1024];
__device__ u16   g_w1b[1024 * 1024];
__device__ int   g_nidx[65536];                  // global feat row of each neighbor
__device__ float g_st[24 * 1024];                // stats/scale/bias slots

#define S(i) (g_st + (i) * 1024)

static __device__ __forceinline__ float bf2f(u16 u) {
  unsigned int x = ((unsigned int)u) << 16;
  return __builtin_bit_cast(float, x);
}
static __device__ __forceinline__ u16 f2bf(float f) {
  unsigned int x = __builtin_bit_cast(unsigned int, f);
  x += 0x7fffu + ((x >> 16) & 1u);   // RNE
  return (u16)(x >> 16);
}
static __device__ __forceinline__ f32x4 mfma16x16(s16x8 a, s16x8 b, f32x4 c) {
  return __builtin_amdgcn_mfma_f32_16x16x32_bf16(
      __builtin_bit_cast(bf16x8, a), __builtin_bit_cast(bf16x8, b), c, 0, 0, 0);
}
static __device__ __forceinline__ void gl_lds16(const void* g, void* l) {
  __builtin_amdgcn_global_load_lds((const __attribute__((address_space(1))) void*)g,
                                   (__attribute__((address_space(3))) void*)l, 16, 0, 0);
}

// ---------------- zero stats accumulators ----------------
__global__ void k_zero() {
  int i = blockIdx.x * 256 + threadIdx.x;
  if (i < 12 * 1024) g_st[i] = 0.f;
}

// ---------------- stage 1a: y1[8192,64] = xyz @ w_c1^T, + channel sums ----------------
__global__ void k_lin1(const float* __restrict__ xyz, const float* __restrict__ w) {
  __shared__ float ls[64], lq[64];
  int t = threadIdx.x;
  if (t < 64) { ls[t] = 0.f; lq[t] = 0.f; }
  __syncthreads();
  int e = blockIdx.x * 256 + t;      // 8192*64, grid 2048
  int row = e >> 6, ch = e & 63;
  float x0 = xyz[row * 3], x1 = xyz[row * 3 + 1], x2 = xyz[row * 3 + 2];
  float v = x0 * w[ch * 3] + x1 * w[ch * 3 + 1] + x2 * w[ch * 3 + 2];
  g_y1[e] = v;
  atomicAdd(&ls[ch], v);
  atomicAdd(&lq[ch], v * v);
  __syncthreads();
  if (t < 64) { atomicAdd(&S(0)[t], ls[t]); atomicAdd(&S(1)[t], lq[t]); }
}

// ---------------- stats -> scale/bias ----------------
__global__ void k_stats(const float* __restrict__ g, const float* __restrict__ b,
                        int si_s, int si_q, int si_sc, int si_bi, float invcnt) {
  int c = blockIdx.x * 64 + threadIdx.x;
  float m = S(si_s)[c] * invcnt;
  float v = S(si_q)[c] * invcnt - m * m;
  float sc = g[c] * rsqrtf(v + BN_EPS);
  S(si_sc)[c] = sc;
  S(si_bi)[c] = b[c] - m * sc;
}

// ---------------- stage 1b: h2pre[8192,256] = relu(bn(y1)) @ w_c2^T ----------------
__global__ void k_lin2(const float* __restrict__ w) {
  __shared__ float hrow[64];
  int t = threadIdx.x;         // channel 0..255
  float wr[64];
#pragma unroll
  for (int i = 0; i < 64; i++) wr[i] = w[t * 64 + i];
  const float* sc1 = S(12);
  const float* bi1 = S(13);
  float ps = 0.f, pq = 0.f;
  int r0 = blockIdx.x * 16;    // grid 512
  for (int r = 0; r < 16; r++) {
    if (t < 64) {
      float v = g_y1[(r0 + r) * 64 + t];
      v = v * sc1[t] + bi1[t];
      hrow[t] = v > 0.f ? v : 0.f;
    }
    __syncthreads();
    float acc = 0.f;
#pragma unroll
    for (int i = 0; i < 64; i++) acc += hrow[i] * wr[i];
    g_h2pre[(r0 + r) * 256 + t] = acc;
    ps += acc;
    pq += acc * acc;
    __syncthreads();
  }
  atomicAdd(&S(2)[t], ps);
  atomicAdd(&S(3)[t], pq);
}

// ---------------- bn+relu f32 -> bf16 (h2pre -> h2b) ----------------
__global__ void k_bnrelu_h2() {
  int i = blockIdx.x * 256 + threadIdx.x;  // grid 8192
  if (i >= 8192 * 256) return;
  int c = i & 255;
  float v = g_h2pre[i] * S(14)[c] + S(15)[c];
  g_h2b[i] = f2bf(v > 0.f ? v : 0.f);
}

// ---------------- kNN (k=8): g_nidx[row] = GLOBAL feat row of neighbor ----------------
__global__ void k_knn(const float* __restrict__ xyz) {
  __shared__ float X[2048], Y[2048], Z[2048], SQ[2048];
  int b = blockIdx.x >> 3;
  int t = threadIdx.x;
  const float* xb = xyz + (size_t)b * 2048 * 3;
  for (int j = t; j < 2048; j += 256) {
    float x = xb[j * 3], y = xb[j * 3 + 1], z = xb[j * 3 + 2];
    X[j] = x; Y[j] = y; Z[j] = z; SQ[j] = x * x + y * y + z * z;
  }
  __syncthreads();
  int qn = (blockIdx.x & 7) * 256 + t;
  float qx = X[qn], qy = Y[qn], qz = Z[qn], qsq = SQ[qn];
  float bd[8];
  int bi[8];
#pragma unroll
  for (int i = 0; i < 8; i++) { bd[i] = 1e30f; bi[i] = 0; }
  for (int j = 0; j < 2048; j++) {
    float d = qsq + SQ[j] - 2.0f * (qx * X[j] + qy * Y[j] + qz * Z[j]);
    if (d < bd[7]) {
      bd[7] = d; bi[7] = j;
#pragma unroll
      for (int p = 7; p > 0; p--) {
        if (bd[p] < bd[p - 1]) {
          float td = bd[p]; bd[p] = bd[p - 1]; bd[p - 1] = td;
          int ti = bi[p]; bi[p] = bi[p - 1]; bi[p - 1] = ti;
        }
      }
    }
  }
  int base = (b * 2048 + qn) * 8;
#pragma unroll
  for (int i = 0; i < 8; i++) g_nidx[base + i] = b * 2048 + bi[i];
}

// ------- weight prep: which 0=wm0a(cat) 1=w0b 2=wm1a(cat) 3=w1b -------
__global__ void k_prep_w(const float* __restrict__ src, int which, int K, int half, int n) {
  int i = blockIdx.x * 256 + threadIdx.x;
  if (i >= n) return;
  int col = i % K;
  float v = src[i];
  if (half && col >= half) v -= src[i - half];   // W2 - W1 fold
  u16* dst = which == 0 ? g_wm0a : which == 1 ? g_w0b : which == 2 ? g_wm1a : g_w1b;
  dst[i] = f2bf(v);
}

// ---------------- gather-GEMM: Z[65536, N] = A' @ Wmod^T + stats ----------------
// A'[row] = concat(feat[nidx[row]], feat[row>>3]), K = 2*C.
// 128x128 tile, BK=32, 4 waves (2x2), 16x16x32 bf16 MFMA, global_load_lds staging.
__global__ __launch_bounds__(256) void k_gemm_gather(int layer, int C, int N,
                                                     int si_s, int si_q) {
  __shared__ u16 As[128 * 32];
  __shared__ u16 Bs[128 * 32];
  __shared__ float cs[128], cq[128];
  const u16* feat = layer == 0 ? g_h2b : g_hl0b;
  const u16* W = layer == 0 ? g_wm0a : g_wm1a;
  int t = threadIdx.x, lane = t & 63, wid = t >> 6;
  int bx = blockIdx.x, by = blockIdx.y;
  int wrow = wid & 1, wcol = wid >> 1;
  int K = 2 * C;
  int r0 = t >> 2, r1 = 64 + (t >> 2), kc = t & 3;
  int nb0 = g_nidx[by * 128 + r0], nb1 = g_nidx[by * 128 + r1];
  int ct0 = (by * 128 + r0) >> 3, ct1 = (by * 128 + r1) >> 3;

  f32x4 acc[4][4];
#pragma unroll
  for (int m = 0; m < 4; m++)
#pragma unroll
    for (int n = 0; n < 4; n++) acc[m][n] = f32x4{0.f, 0.f, 0.f, 0.f};

  const u16* Wb = W + (size_t)bx * 128 * K;
  int l15 = lane & 15, ko = (lane >> 4) * 8;
  int nk = K >> 5;

  for (int ks = 0; ks < nk; ks++) {
    int kg = ks * 32;
    int srow0, srow1, coff;
    if (kg < C) { srow0 = nb0; srow1 = nb1; coff = kg + kc * 8; }
    else        { srow0 = ct0; srow1 = ct1; coff = kg - C + kc * 8; }
    gl_lds16(feat + (size_t)srow0 * C + coff, &As[wid * 512]);
    gl_lds16(Wb + (size_t)r0 * K + kg + kc * 8, &Bs[wid * 512]);
    gl_lds16(feat + (size_t)srow1 * C + coff, &As[(4 + wid) * 512]);
    gl_lds16(Wb + (size_t)r1 * K + kg + kc * 8, &Bs[(4 + wid) * 512]);
    __syncthreads();
    s16x8 af[4], bf[4];
#pragma unroll
    for (int m = 0; m < 4; m++)
      af[m] = *(const s16x8*)&As[(wrow * 64 + m * 16 + l15) * 32 + ko];
#pragma unroll
    for (int n = 0; n < 4; n++)
      bf[n] = *(const s16x8*)&Bs[(wcol * 64 + n * 16 + l15) * 32 + ko];
#pragma unroll
    for (int m = 0; m < 4; m++)
#pragma unroll
      for (int n = 0; n < 4; n++) acc[m][n] = mfma16x16(af[m], bf[n], acc[m][n]);
    __syncthreads();
  }

  if (t < 128) { cs[t] = 0.f; cq[t] = 0.f; }
  __syncthreads();
#pragma unroll
  for (int n = 0; n < 4; n++) {
    float ssum = 0.f, ssq = 0.f;
#pragma unroll
    for (int m = 0; m < 4; m++)
#pragma unroll
      for (int j = 0; j < 4; j++) {
        float v = acc[m][n][j];
        ssum += v;
        ssq += v * v;
      }
    int col = wcol * 64 + n * 16 + l15;
    atomicAdd(&cs[col], ssum);
    atomicAdd(&cq[col], ssq);
  }
#pragma unroll
  for (int m = 0; m < 4; m++) {
    int rbase = by * 128 + wrow * 64 + m * 16 + ((lane >> 4) << 2);
#pragma unroll
    for (int n = 0; n < 4; n++) {
      int col = bx * 128 + wcol * 64 + n * 16 + l15;
#pragma unroll
      for (int j = 0; j < 4; j++) g_Z[(size_t)(rbase + j) * N + col] = f2bf(acc[m][n][j]);
    }
  }
  __syncthreads();
  if (t < 128) {
    atomicAdd(&S(si_s)[bx * 128 + t], cs[t]);
    atomicAdd(&S(si_q)[bx * 128 + t], cq[t]);
  }
}

// ---------------- in-place bn+relu on bf16 Z ----------------
__global__ void k_bnrelu_z(int si_sc, int si_bi, int cmask, size_t n8) {
  size_t i = (size_t)blockIdx.x * 256 + threadIdx.x;
  size_t stride = (size_t)gridDim.x * 256;
  const float* sc = S(si_sc);
  const float* bi = S(si_bi);
  for (; i < n8; i += stride) {
    u16x8 v = *(const u16x8*)(g_Z + i * 8);
    int c0 = (int)((i * 8) & (size_t)cmask);
    u16x8 o;
#pragma unroll
    for (int j = 0; j < 8; j++) {
      float f = bf2f(v[j]) * sc[c0 + j] + bi[c0 + j];
      o[j] = f2bf(f > 0.f ? f : 0.f);
    }
    *(u16x8*)(g_Z + i * 8) = o;
  }
}

// -------- GEMM + in-epilogue max over k=8: pooled[8192,N] (pre-BN) + stats --------
__global__ __launch_bounds__(256) void k_gemm_pool(int layer, int K, int N,
                                                   int si_s, int si_q) {
  __shared__ u16 As[128 * 32];
  __shared__ u16 Bs[128 * 32];
  __shared__ float cs[128], cq[128];
  const u16* W = layer == 0 ? g_w0b : g_w1b;
  int t = threadIdx.x, lane = t & 63, wid = t >> 6;
  int bx = blockIdx.x, by = blockIdx.y;
  int wrow = wid & 1, wcol = wid >> 1;
  int r0 = t >> 2, r1 = 64 + (t >> 2), kc = t & 3;

  f32x4 acc[4][4];
#pragma unroll
  for (int m = 0; m < 4; m++)
#pragma unroll
    for (int n = 0; n < 4; n++) acc[m][n] = f32x4{0.f, 0.f, 0.f, 0.f};

  const u16* Ab = g_Z + (size_t)by * 128 * K;
  const u16* Wb = W + (size_t)bx * 128 * K;
  int l15 = lane & 15, ko = (lane >> 4) * 8;
  int nk = K >> 5;

  for (int ks = 0; ks < nk; ks++) {
    int kg = ks * 32;
    gl_lds16(Ab + (size_t)r0 * K + kg + kc * 8, &As[wid * 512]);
    gl_lds16(Wb + (size_t)r0 * K + kg + kc * 8, &Bs[wid * 512]);
    gl_lds16(Ab + (size_t)r1 * K + kg + kc * 8, &As[(4 + wid) * 512]);
    gl_lds16(Wb + (size_t)r1 * K + kg + kc * 8, &Bs[(4 + wid) * 512]);
    __syncthreads();
    s16x8 af[4], bf[4];
#pragma unroll
    for (int m = 0; m < 4; m++)
      af[m] = *(const s16x8*)&As[(wrow * 64 + m * 16 + l15) * 32 + ko];
#pragma unroll
    for (int n = 0; n < 4; n++)
      bf[n] = *(const s16x8*)&Bs[(wcol * 64 + n * 16 + l15) * 32 + ko];
#pragma unroll
    for (int m = 0; m < 4; m++)
#pragma unroll
      for (int n = 0; n < 4; n++) acc[m][n] = mfma16x16(af[m], bf[n], acc[m][n]);
    __syncthreads();
  }

  if (t < 128) { cs[t] = 0.f; cq[t] = 0.f; }
  __syncthreads();
#pragma unroll
  for (int n = 0; n < 4; n++) {
    float ssum = 0.f, ssq = 0.f;
#pragma unroll
    for (int m = 0; m < 4; m++)
#pragma unroll
      for (int j = 0; j < 4; j++) {
        float v = acc[m][n][j];
        ssum += v;
        ssq += v * v;
      }
    int col = wcol * 64 + n * 16 + l15;
    atomicAdd(&cs[col], ssum);
    atomicAdd(&cq[col], ssq);
  }
  // max over k=8: rows are bn*8+k. lane holds 4 rows (j); pair with lane^16 -> 8 rows.
#pragma unroll
  for (int m = 0; m < 4; m++) {
    int prow = by * 16 + wrow * 8 + m * 2 + ((lane >> 5) & 1);
#pragma unroll
    for (int n = 0; n < 4; n++) {
      float v4 = fmaxf(fmaxf(acc[m][n][0], acc[m][n][1]), fmaxf(acc[m][n][2], acc[m][n][3]));
      float v8 = fmaxf(v4, __shfl_xor(v4, 16, 64));
      if ((lane & 16) == 0) {
        int col = bx * 128 + wcol * 64 + n * 16 + l15;
        g_pooled[(size_t)prow * N + col] = v8;
      }
    }
  }
  __syncthreads();
  if (t < 128) {
    atomicAdd(&S(si_s)[bx * 128 + t], cs[t]);
    atomicAdd(&S(si_q)[bx * 128 + t], cq[t]);
  }
}

// ---------------- bn+relu pooled f32 -> bf16 feat (local_op 0 only) ----------------
__global__ void k_bnrelu_pool() {
  int i = blockIdx.x * 256 + threadIdx.x;  // grid 16384, n = 8192*512
  if (i >= 8192 * 512) return;
  int c = i & 511;
  float v = g_pooled[i] * S(18)[c] + S(19)[c];
  g_hl0b[i] = f2bf(v > 0.f ? v : 0.f);
}

// ---------------- final: bn+relu pooled[8192,1024] -> out (B,1024,2048) f32 ----------------
__global__ void k_final_t(float* __restrict__ out) {
  __shared__ float tile[64][65];
  int b = blockIdx.z;     // 4
  int nb = blockIdx.y;    // 32
  int cb = blockIdx.x;    // 16
  int t = threadIdx.x;
  int cl = t & 63;
  int c = cb * 64 + cl;
  float sc = S(22)[c], bi = S(23)[c];
  for (int nl = t >> 6; nl < 64; nl += 4) {
    float v = g_pooled[(size_t)(b * 2048 + nb * 64 + nl) * 1024 + c] * sc + bi;
    tile[nl][cl] = v > 0.f ? v : 0.f;
  }
  __syncthreads();
  int nl2 = t & 63;
  for (int ci = t >> 6; ci < 64; ci += 4) {
    out[((size_t)b * 1024 + cb * 64 + ci) * 2048 + nb * 64 + nl2] = tile[nl2][ci];
  }
}

extern "C" void kernel_launch(void* const* d_in, const int* in_sizes, int n_in,
                              void* d_out, int out_size, void* d_ws, size_t ws_size,
                              hipStream_t stream) {
  const float* xyz  = (const float*)d_in[0];
  const float* w_c1 = (const float*)d_in[1];
  const float* g_c1 = (const float*)d_in[2];
  const float* b_c1 = (const float*)d_in[3];
  const float* w_c2 = (const float*)d_in[4];
  const float* g_c2 = (const float*)d_in[5];
  const float* b_c2 = (const float*)d_in[6];
  const float* w_l0a = (const float*)d_in[7];
  const float* g_l0a = (const float*)d_in[8];
  const float* b_l0a = (const float*)d_in[9];
  const float* w_l0b = (const float*)d_in[10];
  const float* g_l0b = (const float*)d_in[11];
  const float* b_l0b = (const float*)d_in[12];
  const float* w_l1a = (const float*)d_in[13];
  const float* g_l1a = (const float*)d_in[14];
  const float* b_l1a = (const float*)d_in[15];
  const float* w_l1b = (const float*)d_in[16];
  const float* g_l1b = (const float*)d_in[17];
  const float* b_l1b = (const float*)d_in[18];
  float* out = (float*)d_out;

  k_zero<<<48, 256, 0, stream>>>();

  // stage 1: xyz -> 64 -> 256 (f32)
  k_lin1<<<2048, 256, 0, stream>>>(xyz, w_c1);
  k_stats<<<1, 64, 0, stream>>>(g_c1, b_c1, 0, 1, 12, 13, 1.f / 8192.f);
  k_lin2<<<512, 256, 0, stream>>>(w_c2);
  k_stats<<<4, 64, 0, stream>>>(g_c2, b_c2, 2, 3, 14, 15, 1.f / 8192.f);
  k_bnrelu_h2<<<8192, 256, 0, stream>>>();

  // kNN shared by both spa_group calls
  k_knn<<<32, 256, 0, stream>>>(xyz);

  // weight prep
  k_prep_w<<<1024, 256, 0, stream>>>(w_l0a, 0, 512, 256, 262144);
  k_prep_w<<<1024, 256, 0, stream>>>(w_l0b, 1, 512, 0, 262144);
  k_prep_w<<<4096, 256, 0, stream>>>(w_l1a, 2, 1024, 512, 1048576);
  k_prep_w<<<4096, 256, 0, stream>>>(w_l1b, 3, 1024, 0, 1048576);

  // local_op 0 (C=256 -> K=512, N=512)
  k_gemm_gather<<<dim3(4, 512), 256, 0, stream>>>(0, 256, 512, 4, 5);
  k_stats<<<8, 64, 0, stream>>>(g_l0a, b_l0a, 4, 5, 16, 17, 1.f / 65536.f);
  k_bnrelu_z<<<2048, 256, 0, stream>>>(16, 17, 511, (size_t)65536 * 512 / 8);
  k_gemm_pool<<<dim3(4, 512), 256, 0, stream>>>(0, 512, 512, 6, 7);
  k_stats<<<8, 64, 0, stream>>>(g_l0b, b_l0b, 6, 7, 18, 19, 1.f / 65536.f);
  k_bnrelu_pool<<<16384, 256, 0, stream>>>();

  // local_op 1 (C=512 -> K=1024, N=1024)
  k_gemm_gather<<<dim3(8, 512), 256, 0, stream>>>(1, 512, 1024, 8, 9);
  k_stats<<<16, 64, 0, stream>>>(g_l1a, b_l1a, 8, 9, 20, 21, 1.f / 65536.f);
  k_bnrelu_z<<<2048, 256, 0, stream>>>(20, 21, 1023, (size_t)65536 * 1024 / 8);
  k_gemm_pool<<<dim3(8, 512), 256, 0, stream>>>(1, 1024, 1024, 10, 11);
  k_stats<<<16, 64, 0, stream>>>(g_l1b, b_l1b, 10, 11, 22, 23, 1.f / 65536.f);
  k_final_t<<<dim3(16, 32, 4), 256, 0, stream>>>(out);
}

// Round 4
// 1176.413 us; speedup vs baseline: 1.0726x; 1.0726x over previous
//
#include <hip/hip_runtime.h>

typedef unsigned short u16;
typedef __attribute__((ext_vector_type(8))) short s16x8;
typedef __attribute__((ext_vector_type(8))) __bf16 bf16x8;
typedef __attribute__((ext_vector_type(8))) unsigned short u16x8;
typedef __attribute__((ext_vector_type(4))) float f32x4;

#define BN_EPS 1e-5f

// ---------- static device buffers (~187 MiB .bss; d_ws not used) ----------
__device__ u16   g_Z[(size_t)65536 * 1024];      // 128 MiB GEMM-a output (l0 uses stride 512)
__device__ float g_pooled[(size_t)8192 * 1024];  // 32 MiB pooled pre-BN
__device__ float g_h2pre[8192 * 256];            // 8 MiB
__device__ u16   g_h2b[8192 * 256];              // 4 MiB feat0 bf16
__device__ u16   g_hl0b[8192 * 512];             // 8 MiB feat1 bf16
__device__ float g_y1[8192 * 64];                // 2 MiB
__device__ u16   g_wm0a[512 * 512];              // [W1 | W2-W1] bf16
__device__ u16   g_w0b[512 * 512];
__device__ u16   g_wm1a[1024 * 1024];
__device__ u16   g_w1b[1024 * 1024];
__device__ int   g_nidx[65536];                  // global feat row of each neighbor
__device__ float g_st[24 * 1024];                // stats/scale/bias slots

#define S(i) (g_st + (i) * 1024)

static __device__ __forceinline__ float bf2f(u16 u) {
  unsigned int x = ((unsigned int)u) << 16;
  return __builtin_bit_cast(float, x);
}
static __device__ __forceinline__ u16 f2bf(float f) {
  unsigned int x = __builtin_bit_cast(unsigned int, f);
  x += 0x7fffu + ((x >> 16) & 1u);   // RNE
  return (u16)(x >> 16);
}
static __device__ __forceinline__ f32x4 mfma16x16(s16x8 a, s16x8 b, f32x4 c) {
  return __builtin_amdgcn_mfma_f32_16x16x32_bf16(
      __builtin_bit_cast(bf16x8, a), __builtin_bit_cast(bf16x8, b), c, 0, 0, 0);
}
static __device__ __forceinline__ void gl_lds16(const void* g, void* l) {
  __builtin_amdgcn_global_load_lds((const __attribute__((address_space(1))) void*)g,
                                   (__attribute__((address_space(3))) void*)l, 16, 0, 0);
}

// ---------------- zero stats accumulators ----------------
__global__ void k_zero() {
  int i = blockIdx.x * 256 + threadIdx.x;
  if (i < 12 * 1024) g_st[i] = 0.f;
}

// ---------------- stage 1a: y1[8192,64] = xyz @ w_c1^T, + channel sums ----------------
__global__ void k_lin1(const float* __restrict__ xyz, const float* __restrict__ w) {
  __shared__ float ls[64], lq[64];
  int t = threadIdx.x;
  if (t < 64) { ls[t] = 0.f; lq[t] = 0.f; }
  __syncthreads();
  int e = blockIdx.x * 256 + t;      // 8192*64, grid 2048
  int row = e >> 6, ch = e & 63;
  float x0 = xyz[row * 3], x1 = xyz[row * 3 + 1], x2 = xyz[row * 3 + 2];
  float v = x0 * w[ch * 3] + x1 * w[ch * 3 + 1] + x2 * w[ch * 3 + 2];
  g_y1[e] = v;
  atomicAdd(&ls[ch], v);
  atomicAdd(&lq[ch], v * v);
  __syncthreads();
  if (t < 64) { atomicAdd(&S(0)[t], ls[t]); atomicAdd(&S(1)[t], lq[t]); }
}

// ---------------- stats -> scale/bias ----------------
__global__ void k_stats(const float* __restrict__ g, const float* __restrict__ b,
                        int si_s, int si_q, int si_sc, int si_bi, float invcnt) {
  int c = blockIdx.x * 64 + threadIdx.x;
  float m = S(si_s)[c] * invcnt;
  float v = S(si_q)[c] * invcnt - m * m;
  float sc = g[c] * rsqrtf(v + BN_EPS);
  S(si_sc)[c] = sc;
  S(si_bi)[c] = b[c] - m * sc;
}

// ---------------- stage 1b: h2pre[8192,256] = relu(bn(y1)) @ w_c2^T ----------------
__global__ void k_lin2(const float* __restrict__ w) {
  __shared__ float hrow[64];
  int t = threadIdx.x;         // channel 0..255
  float wr[64];
#pragma unroll
  for (int i = 0; i < 64; i++) wr[i] = w[t * 64 + i];
  const float* sc1 = S(12);
  const float* bi1 = S(13);
  float ps = 0.f, pq = 0.f;
  int r0 = blockIdx.x * 16;    // grid 512
  for (int r = 0; r < 16; r++) {
    if (t < 64) {
      float v = g_y1[(r0 + r) * 64 + t];
      v = v * sc1[t] + bi1[t];
      hrow[t] = v > 0.f ? v : 0.f;
    }
    __syncthreads();
    float acc = 0.f;
#pragma unroll
    for (int i = 0; i < 64; i++) acc += hrow[i] * wr[i];
    g_h2pre[(r0 + r) * 256 + t] = acc;
    ps += acc;
    pq += acc * acc;
    __syncthreads();
  }
  atomicAdd(&S(2)[t], ps);
  atomicAdd(&S(3)[t], pq);
}

// ---------------- bn+relu f32 -> bf16 (h2pre -> h2b) ----------------
__global__ void k_bnrelu_h2() {
  int i = blockIdx.x * 256 + threadIdx.x;  // grid 8192
  if (i >= 8192 * 256) return;
  int c = i & 255;
  float v = g_h2pre[i] * S(14)[c] + S(15)[c];
  g_h2b[i] = f2bf(v > 0.f ? v : 0.f);
}

// ---------------- kNN (k=8): g_nidx[row] = GLOBAL feat row of neighbor ----------------
__global__ void k_knn(const float* __restrict__ xyz) {
  __shared__ float X[2048], Y[2048], Z[2048], SQ[2048];
  int b = blockIdx.x >> 3;
  int t = threadIdx.x;
  const float* xb = xyz + (size_t)b * 2048 * 3;
  for (int j = t; j < 2048; j += 256) {
    float x = xb[j * 3], y = xb[j * 3 + 1], z = xb[j * 3 + 2];
    X[j] = x; Y[j] = y; Z[j] = z; SQ[j] = x * x + y * y + z * z;
  }
  __syncthreads();
  int qn = (blockIdx.x & 7) * 256 + t;
  float qx = X[qn], qy = Y[qn], qz = Z[qn], qsq = SQ[qn];
  float bd[8];
  int bi[8];
#pragma unroll
  for (int i = 0; i < 8; i++) { bd[i] = 1e30f; bi[i] = 0; }
  for (int j = 0; j < 2048; j++) {
    float d = qsq + SQ[j] - 2.0f * (qx * X[j] + qy * Y[j] + qz * Z[j]);
    if (d < bd[7]) {
      bd[7] = d; bi[7] = j;
#pragma unroll
      for (int p = 7; p > 0; p--) {
        if (bd[p] < bd[p - 1]) {
          float td = bd[p]; bd[p] = bd[p - 1]; bd[p - 1] = td;
          int ti = bi[p]; bi[p] = bi[p - 1]; bi[p - 1] = ti;
        }
      }
    }
  }
  int base = (b * 2048 + qn) * 8;
#pragma unroll
  for (int i = 0; i < 8; i++) g_nidx[base + i] = b * 2048 + bi[i];
}

// ------- weight prep: which 0=wm0a(cat) 1=w0b 2=wm1a(cat) 3=w1b -------
__global__ void k_prep_w(const float* __restrict__ src, int which, int K, int half, int n) {
  int i = blockIdx.x * 256 + threadIdx.x;
  if (i >= n) return;
  int col = i % K;
  float v = src[i];
  if (half && col >= half) v -= src[i - half];   // W2 - W1 fold
  u16* dst = which == 0 ? g_wm0a : which == 1 ? g_w0b : which == 2 ? g_wm1a : g_w1b;
  dst[i] = f2bf(v);
}

// ---------------- gather-GEMM: Z[65536, N] = A' @ Wmod^T + stats ----------------
// A'[row] = concat(feat[nidx[row]], feat[row>>3]), K = 2*C.
// 128x128 tile, BK=32, 2-phase LDS dbuf, XCD-chunked swizzle, 16x16x32 bf16 MFMA.
__global__ __launch_bounds__(256) void k_gemm_gather(int layer, int C, int N,
                                                     int si_s, int si_q, int lbx) {
  __shared__ u16 As[2][128 * 32];
  __shared__ u16 Bs[2][128 * 32];
  __shared__ float cs[128], cq[128];
  const u16* feat = layer == 0 ? g_h2b : g_hl0b;
  const u16* W = layer == 0 ? g_wm0a : g_wm1a;
  int t = threadIdx.x, lane = t & 63, wid = t >> 6;
  // T1: XCD-chunked block swizzle (gridDim.x % 8 == 0); bx fastest within a chunk
  int chunk = gridDim.x >> 3;
  int idx = (blockIdx.x & 7) * chunk + (blockIdx.x >> 3);
  int bx = idx & ((1 << lbx) - 1), by = idx >> lbx;
  int wrow = wid & 1, wcol = wid >> 1;
  int K = 2 * C;
  int r0 = t >> 2, r1 = 64 + (t >> 2), kc = t & 3;
  int nb0 = g_nidx[by * 128 + r0], nb1 = g_nidx[by * 128 + r1];
  int ct0 = (by * 128 + r0) >> 3, ct1 = (by * 128 + r1) >> 3;

  f32x4 acc[4][4];
#pragma unroll
  for (int m = 0; m < 4; m++)
#pragma unroll
    for (int n = 0; n < 4; n++) acc[m][n] = f32x4{0.f, 0.f, 0.f, 0.f};

  const u16* Wb = W + (size_t)bx * 128 * K;
  int l15 = lane & 15, ko = (lane >> 4) * 8;
  int nk = K >> 5;

#define STAGE_G(KG, BUF)                                                     \
  {                                                                          \
    int kg_ = (KG);                                                          \
    int srow0, srow1, coff;                                                  \
    if (kg_ < C) { srow0 = nb0; srow1 = nb1; coff = kg_ + kc * 8; }          \
    else         { srow0 = ct0; srow1 = ct1; coff = kg_ - C + kc * 8; }      \
    gl_lds16(feat + (size_t)srow0 * C + coff, &As[BUF][wid * 512]);          \
    gl_lds16(Wb + (size_t)r0 * K + kg_ + kc * 8, &Bs[BUF][wid * 512]);       \
    gl_lds16(feat + (size_t)srow1 * C + coff, &As[BUF][(4 + wid) * 512]);    \
    gl_lds16(Wb + (size_t)r1 * K + kg_ + kc * 8, &Bs[BUF][(4 + wid) * 512]); \
  }

  STAGE_G(0, 0);
  __syncthreads();
  int cur = 0;
  for (int ks = 0; ks < nk; ks++) {
    if (ks + 1 < nk) STAGE_G((ks + 1) * 32, cur ^ 1);
    s16x8 af[4], bf[4];
#pragma unroll
    for (int m = 0; m < 4; m++)
      af[m] = *(const s16x8*)&As[cur][(wrow * 64 + m * 16 + l15) * 32 + ko];
#pragma unroll
    for (int n = 0; n < 4; n++)
      bf[n] = *(const s16x8*)&Bs[cur][(wcol * 64 + n * 16 + l15) * 32 + ko];
#pragma unroll
    for (int m = 0; m < 4; m++)
#pragma unroll
      for (int n = 0; n < 4; n++) acc[m][n] = mfma16x16(af[m], bf[n], acc[m][n]);
    __syncthreads();   // drains this iter's prefetch; next tile ready
    cur ^= 1;
  }
#undef STAGE_G

  if (t < 128) { cs[t] = 0.f; cq[t] = 0.f; }
  __syncthreads();
#pragma unroll
  for (int n = 0; n < 4; n++) {
    float ssum = 0.f, ssq = 0.f;
#pragma unroll
    for (int m = 0; m < 4; m++)
#pragma unroll
      for (int j = 0; j < 4; j++) {
        float v = acc[m][n][j];
        ssum += v;
        ssq += v * v;
      }
    int col = wcol * 64 + n * 16 + l15;
    atomicAdd(&cs[col], ssum);
    atomicAdd(&cq[col], ssq);
  }
#pragma unroll
  for (int m = 0; m < 4; m++) {
    int rbase = by * 128 + wrow * 64 + m * 16 + ((lane >> 4) << 2);
#pragma unroll
    for (int n = 0; n < 4; n++) {
      int col = bx * 128 + wcol * 64 + n * 16 + l15;
#pragma unroll
      for (int j = 0; j < 4; j++) g_Z[(size_t)(rbase + j) * N + col] = f2bf(acc[m][n][j]);
    }
  }
  __syncthreads();
  if (t < 128) {
    atomicAdd(&S(si_s)[bx * 128 + t], cs[t]);
    atomicAdd(&S(si_q)[bx * 128 + t], cq[t]);
  }
}

// ---------------- in-place bn+relu on bf16 Z ----------------
__global__ void k_bnrelu_z(int si_sc, int si_bi, int cmask, size_t n8) {
  size_t i = (size_t)blockIdx.x * 256 + threadIdx.x;
  size_t stride = (size_t)gridDim.x * 256;
  const float* sc = S(si_sc);
  const float* bi = S(si_bi);
  for (; i < n8; i += stride) {
    u16x8 v = *(const u16x8*)(g_Z + i * 8);
    int c0 = (int)((i * 8) & (size_t)cmask);
    u16x8 o;
#pragma unroll
    for (int j = 0; j < 8; j++) {
      float f = bf2f(v[j]) * sc[c0 + j] + bi[c0 + j];
      o[j] = f2bf(f > 0.f ? f : 0.f);
    }
    *(u16x8*)(g_Z + i * 8) = o;
  }
}

// -------- GEMM + in-epilogue max over k=8: pooled[8192,N] (pre-BN) + stats --------
__global__ __launch_bounds__(256) void k_gemm_pool(int layer, int K, int N,
                                                   int si_s, int si_q, int lbx) {
  __shared__ u16 As[2][128 * 32];
  __shared__ u16 Bs[2][128 * 32];
  __shared__ float cs[128], cq[128];
  const u16* W = layer == 0 ? g_w0b : g_w1b;
  int t = threadIdx.x, lane = t & 63, wid = t >> 6;
  int chunk = gridDim.x >> 3;
  int idx = (blockIdx.x & 7) * chunk + (blockIdx.x >> 3);
  int bx = idx & ((1 << lbx) - 1), by = idx >> lbx;
  int wrow = wid & 1, wcol = wid >> 1;
  int r0 = t >> 2, r1 = 64 + (t >> 2), kc = t & 3;

  f32x4 acc[4][4];
#pragma unroll
  for (int m = 0; m < 4; m++)
#pragma unroll
    for (int n = 0; n < 4; n++) acc[m][n] = f32x4{0.f, 0.f, 0.f, 0.f};

  const u16* Ab = g_Z + (size_t)by * 128 * K;
  const u16* Wb = W + (size_t)bx * 128 * K;
  int l15 = lane & 15, ko = (lane >> 4) * 8;
  int nk = K >> 5;

#define STAGE_P(KG, BUF)                                                      \
  {                                                                           \
    int kg_ = (KG);                                                           \
    gl_lds16(Ab + (size_t)r0 * K + kg_ + kc * 8, &As[BUF][wid * 512]);        \
    gl_lds16(Wb + (size_t)r0 * K + kg_ + kc * 8, &Bs[BUF][wid * 512]);        \
    gl_lds16(Ab + (size_t)r1 * K + kg_ + kc * 8, &As[BUF][(4 + wid) * 512]);  \
    gl_lds16(Wb + (size_t)r1 * K + kg_ + kc * 8, &Bs[BUF][(4 + wid) * 512]);  \
  }

  STAGE_P(0, 0);
  __syncthreads();
  int cur = 0;
  for (int ks = 0; ks < nk; ks++) {
    if (ks + 1 < nk) STAGE_P((ks + 1) * 32, cur ^ 1);
    s16x8 af[4], bf[4];
#pragma unroll
    for (int m = 0; m < 4; m++)
      af[m] = *(const s16x8*)&As[cur][(wrow * 64 + m * 16 + l15) * 32 + ko];
#pragma unroll
    for (int n = 0; n < 4; n++)
      bf[n] = *(const s16x8*)&Bs[cur][(wcol * 64 + n * 16 + l15) * 32 + ko];
#pragma unroll
    for (int m = 0; m < 4; m++)
#pragma unroll
      for (int n = 0; n < 4; n++) acc[m][n] = mfma16x16(af[m], bf[n], acc[m][n]);
    __syncthreads();
    cur ^= 1;
  }
#undef STAGE_P

  if (t < 128) { cs[t] = 0.f; cq[t] = 0.f; }
  __syncthreads();
#pragma unroll
  for (int n = 0; n < 4; n++) {
    float ssum = 0.f, ssq = 0.f;
#pragma unroll
    for (int m = 0; m < 4; m++)
#pragma unroll
      for (int j = 0; j < 4; j++) {
        float v = acc[m][n][j];
        ssum += v;
        ssq += v * v;
      }
    int col = wcol * 64 + n * 16 + l15;
    atomicAdd(&cs[col], ssum);
    atomicAdd(&cq[col], ssq);
  }
  // max over k=8: rows are bn*8+k. lane holds 4 rows (j); pair with lane^16 -> 8 rows.
#pragma unroll
  for (int m = 0; m < 4; m++) {
    int prow = by * 16 + wrow * 8 + m * 2 + ((lane >> 5) & 1);
#pragma unroll
    for (int n = 0; n < 4; n++) {
      float v4 = fmaxf(fmaxf(acc[m][n][0], acc[m][n][1]), fmaxf(acc[m][n][2], acc[m][n][3]));
      float v8 = fmaxf(v4, __shfl_xor(v4, 16, 64));
      if ((lane & 16) == 0) {
        int col = bx * 128 + wcol * 64 + n * 16 + l15;
        g_pooled[(size_t)prow * N + col] = v8;
      }
    }
  }
  __syncthreads();
  if (t < 128) {
    atomicAdd(&S(si_s)[bx * 128 + t], cs[t]);
    atomicAdd(&S(si_q)[bx * 128 + t], cq[t]);
  }
}

// ---------------- bn+relu pooled f32 -> bf16 feat (local_op 0 only) ----------------
__global__ void k_bnrelu_pool() {
  int i = blockIdx.x * 256 + threadIdx.x;  // grid 16384, n = 8192*512
  if (i >= 8192 * 512) return;
  int c = i & 511;
  float v = g_pooled[i] * S(18)[c] + S(19)[c];
  g_hl0b[i] = f2bf(v > 0.f ? v : 0.f);
}

// ---------------- final: bn+relu pooled[8192,1024] -> out (B,1024,2048) f32 ----------------
__global__ void k_final_t(float* __restrict__ out) {
  __shared__ float tile[64][65];
  int b = blockIdx.z;     // 4
  int nb = blockIdx.y;    // 32
  int cb = blockIdx.x;    // 16
  int t = threadIdx.x;
  int cl = t & 63;
  int c = cb * 64 + cl;
  float sc = S(22)[c], bi = S(23)[c];
  for (int nl = t >> 6; nl < 64; nl += 4) {
    float v = g_pooled[(size_t)(b * 2048 + nb * 64 + nl) * 1024 + c] * sc + bi;
    tile[nl][cl] = v > 0.f ? v : 0.f;
  }
  __syncthreads();
  int nl2 = t & 63;
  for (int ci = t >> 6; ci < 64; ci += 4) {
    out[((size_t)b * 1024 + cb * 64 + ci) * 2048 + nb * 64 + nl2] = tile[nl2][ci];
  }
}

extern "C" void kernel_launch(void* const* d_in, const int* in_sizes, int n_in,
                              void* d_out, int out_size, void* d_ws, size_t ws_size,
                              hipStream_t stream) {
  const float* xyz  = (const float*)d_in[0];
  const float* w_c1 = (const float*)d_in[1];
  const float* g_c1 = (const float*)d_in[2];
  const float* b_c1 = (const float*)d_in[3];
  const float* w_c2 = (const float*)d_in[4];
  const float* g_c2 = (const float*)d_in[5];
  const float* b_c2 = (const float*)d_in[6];
  const float* w_l0a = (const float*)d_in[7];
  const float* g_l0a = (const float*)d_in[8];
  const float* b_l0a = (const float*)d_in[9];
  const float* w_l0b = (const float*)d_in[10];
  const float* g_l0b = (const float*)d_in[11];
  const float* b_l0b = (const float*)d_in[12];
  const float* w_l1a = (const float*)d_in[13];
  const float* g_l1a = (const float*)d_in[14];
  const float* b_l1a = (const float*)d_in[15];
  const float* w_l1b = (const float*)d_in[16];
  const float* g_l1b = (const float*)d_in[17];
  const float* b_l1b = (const float*)d_in[18];
  float* out = (float*)d_out;

  k_zero<<<48, 256, 0, stream>>>();

  // stage 1: xyz -> 64 -> 256 (f32)
  k_lin1<<<2048, 256, 0, stream>>>(xyz, w_c1);
  k_stats<<<1, 64, 0, stream>>>(g_c1, b_c1, 0, 1, 12, 13, 1.f / 8192.f);
  k_lin2<<<512, 256, 0, stream>>>(w_c2);
  k_stats<<<4, 64, 0, stream>>>(g_c2, b_c2, 2, 3, 14, 15, 1.f / 8192.f);
  k_bnrelu_h2<<<8192, 256, 0, stream>>>();

  // kNN shared by both spa_group calls
  k_knn<<<32, 256, 0, stream>>>(xyz);

  // weight prep
  k_prep_w<<<1024, 256, 0, stream>>>(w_l0a, 0, 512, 256, 262144);
  k_prep_w<<<1024, 256, 0, stream>>>(w_l0b, 1, 512, 0, 262144);
  k_prep_w<<<4096, 256, 0, stream>>>(w_l1a, 2, 1024, 512, 1048576);
  k_prep_w<<<4096, 256, 0, stream>>>(w_l1b, 3, 1024, 0, 1048576);

  // local_op 0 (C=256 -> K=512, N=512): grid 4x512 -> 1D 2048, lbx=2
  k_gemm_gather<<<2048, 256, 0, stream>>>(0, 256, 512, 4, 5, 2);
  k_stats<<<8, 64, 0, stream>>>(g_l0a, b_l0a, 4, 5, 16, 17, 1.f / 65536.f);
  k_bnrelu_z<<<2048, 256, 0, stream>>>(16, 17, 511, (size_t)65536 * 512 / 8);
  k_gemm_pool<<<2048, 256, 0, stream>>>(0, 512, 512, 6, 7, 2);
  k_stats<<<8, 64, 0, stream>>>(g_l0b, b_l0b, 6, 7, 18, 19, 1.f / 65536.f);
  k_bnrelu_pool<<<16384, 256, 0, stream>>>();

  // local_op 1 (C=512 -> K=1024, N=1024): grid 8x512 -> 1D 4096, lbx=3
  k_gemm_gather<<<4096, 256, 0, stream>>>(1, 512, 1024, 8, 9, 3);
  k_stats<<<16, 64, 0, stream>>>(g_l1a, b_l1a, 8, 9, 20, 21, 1.f / 65536.f);
  k_bnrelu_z<<<2048, 256, 0, stream>>>(20, 21, 1023, (size_t)65536 * 1024 / 8);
  k_gemm_pool<<<4096, 256, 0, stream>>>(1, 1024, 1024, 10, 11, 3);
  k_stats<<<16, 64, 0, stream>>>(g_l1b, b_l1b, 10, 11, 22, 23, 1.f / 65536.f);
  k_final_t<<<dim3(16, 32, 4), 256, 0, stream>>>(out);
}

// Round 5
// 1122.907 us; speedup vs baseline: 1.1237x; 1.0476x over previous
//
#include <hip/hip_runtime.h>

typedef unsigned short u16;
typedef __attribute__((ext_vector_type(8))) short s16x8;
typedef __attribute__((ext_vector_type(8))) __bf16 bf16x8;
typedef __attribute__((ext_vector_type(8))) unsigned short u16x8;
typedef __attribute__((ext_vector_type(4))) float f32x4;

#define BN_EPS 1e-5f

// ---------- static device buffers (~187 MiB .bss; d_ws not used) ----------
__device__ u16   g_Z[(size_t)65536 * 1024];      // 128 MiB GEMM-a output (l0 uses stride 512)
__device__ float g_pooled[(size_t)8192 * 1024];  // 32 MiB pooled pre-BN
__device__ float g_h2pre[8192 * 256];            // 8 MiB
__device__ u16   g_h2b[8192 * 256];              // 4 MiB feat0 bf16
__device__ u16   g_hl0b[8192 * 512];             // 8 MiB feat1 bf16
__device__ float g_y1[8192 * 64];                // 2 MiB
__device__ u16   g_wm0a[512 * 512];              // [W1 | W2-W1] bf16
__device__ u16   g_w0b[512 * 512];
__device__ u16   g_wm1a[1024 * 1024];
__device__ u16   g_w1b[1024 * 1024];
__device__ int   g_nidx[65536];                  // global feat row of each neighbor
__device__ float g_st[24 * 1024];                // stats/scale/bias slots

#define S(i) (g_st + (i) * 1024)

static __device__ __forceinline__ float bf2f(u16 u) {
  unsigned int x = ((unsigned int)u) << 16;
  return __builtin_bit_cast(float, x);
}
static __device__ __forceinline__ u16 f2bf(float f) {
  unsigned int x = __builtin_bit_cast(unsigned int, f);
  x += 0x7fffu + ((x >> 16) & 1u);   // RNE
  return (u16)(x >> 16);
}
static __device__ __forceinline__ f32x4 mfma16x16(s16x8 a, s16x8 b, f32x4 c) {
  return __builtin_amdgcn_mfma_f32_16x16x32_bf16(
      __builtin_bit_cast(bf16x8, a), __builtin_bit_cast(bf16x8, b), c, 0, 0, 0);
}
static __device__ __forceinline__ void gl_lds16(const void* g, void* l) {
  __builtin_amdgcn_global_load_lds((const __attribute__((address_space(1))) void*)g,
                                   (__attribute__((address_space(3))) void*)l, 16, 0, 0);
}

// ---------------- zero stats accumulators ----------------
__global__ void k_zero() {
  int i = blockIdx.x * 256 + threadIdx.x;
  if (i < 12 * 1024) g_st[i] = 0.f;
}

// ---------------- stage 1a: y1[8192,64] = xyz @ w_c1^T, + channel sums ----------------
__global__ void k_lin1(const float* __restrict__ xyz, const float* __restrict__ w) {
  __shared__ float ls[64], lq[64];
  int t = threadIdx.x;
  if (t < 64) { ls[t] = 0.f; lq[t] = 0.f; }
  __syncthreads();
  int e = blockIdx.x * 256 + t;      // 8192*64, grid 2048
  int row = e >> 6, ch = e & 63;
  float x0 = xyz[row * 3], x1 = xyz[row * 3 + 1], x2 = xyz[row * 3 + 2];
  float v = x0 * w[ch * 3] + x1 * w[ch * 3 + 1] + x2 * w[ch * 3 + 2];
  g_y1[e] = v;
  atomicAdd(&ls[ch], v);
  atomicAdd(&lq[ch], v * v);
  __syncthreads();
  if (t < 64) { atomicAdd(&S(0)[t], ls[t]); atomicAdd(&S(1)[t], lq[t]); }
}

// ---------------- stats -> scale/bias ----------------
__global__ void k_stats(const float* __restrict__ g, const float* __restrict__ b,
                        int si_s, int si_q, int si_sc, int si_bi, float invcnt) {
  int c = blockIdx.x * 64 + threadIdx.x;
  float m = S(si_s)[c] * invcnt;
  float v = S(si_q)[c] * invcnt - m * m;
  float sc = g[c] * rsqrtf(v + BN_EPS);
  S(si_sc)[c] = sc;
  S(si_bi)[c] = b[c] - m * sc;
}

// ---------------- stage 1b: h2pre[8192,256] = relu(bn(y1)) @ w_c2^T ----------------
__global__ void k_lin2(const float* __restrict__ w) {
  __shared__ float hrow[64];
  int t = threadIdx.x;         // channel 0..255
  float wr[64];
#pragma unroll
  for (int i = 0; i < 64; i++) wr[i] = w[t * 64 + i];
  const float* sc1 = S(12);
  const float* bi1 = S(13);
  float ps = 0.f, pq = 0.f;
  int r0 = blockIdx.x * 16;    // grid 512
  for (int r = 0; r < 16; r++) {
    if (t < 64) {
      float v = g_y1[(r0 + r) * 64 + t];
      v = v * sc1[t] + bi1[t];
      hrow[t] = v > 0.f ? v : 0.f;
    }
    __syncthreads();
    float acc = 0.f;
#pragma unroll
    for (int i = 0; i < 64; i++) acc += hrow[i] * wr[i];
    g_h2pre[(r0 + r) * 256 + t] = acc;
    ps += acc;
    pq += acc * acc;
    __syncthreads();
  }
  atomicAdd(&S(2)[t], ps);
  atomicAdd(&S(3)[t], pq);
}

// ---------------- bn+relu f32 -> bf16 (h2pre -> h2b) ----------------
__global__ void k_bnrelu_h2() {
  int i = blockIdx.x * 256 + threadIdx.x;  // grid 8192
  if (i >= 8192 * 256) return;
  int c = i & 255;
  float v = g_h2pre[i] * S(14)[c] + S(15)[c];
  g_h2b[i] = f2bf(v > 0.f ? v : 0.f);
}

// ---------------- kNN (k=8): g_nidx[row] = GLOBAL feat row of neighbor ----------------
__global__ void k_knn(const float* __restrict__ xyz) {
  __shared__ float X[2048], Y[2048], Z[2048], SQ[2048];
  int b = blockIdx.x >> 3;
  int t = threadIdx.x;
  const float* xb = xyz + (size_t)b * 2048 * 3;
  for (int j = t; j < 2048; j += 256) {
    float x = xb[j * 3], y = xb[j * 3 + 1], z = xb[j * 3 + 2];
    X[j] = x; Y[j] = y; Z[j] = z; SQ[j] = x * x + y * y + z * z;
  }
  __syncthreads();
  int qn = (blockIdx.x & 7) * 256 + t;
  float qx = X[qn], qy = Y[qn], qz = Z[qn], qsq = SQ[qn];
  float bd[8];
  int bi[8];
#pragma unroll
  for (int i = 0; i < 8; i++) { bd[i] = 1e30f; bi[i] = 0; }
  for (int j = 0; j < 2048; j++) {
    float d = qsq + SQ[j] - 2.0f * (qx * X[j] + qy * Y[j] + qz * Z[j]);
    if (d < bd[7]) {
      bd[7] = d; bi[7] = j;
#pragma unroll
      for (int p = 7; p > 0; p--) {
        if (bd[p] < bd[p - 1]) {
          float td = bd[p]; bd[p] = bd[p - 1]; bd[p - 1] = td;
          int ti = bi[p]; bi[p] = bi[p - 1]; bi[p - 1] = ti;
        }
      }
    }
  }
  int base = (b * 2048 + qn) * 8;
#pragma unroll
  for (int i = 0; i < 8; i++) g_nidx[base + i] = b * 2048 + bi[i];
}

// ------- weight prep: which 0=wm0a(cat) 1=w0b 2=wm1a(cat) 3=w1b -------
__global__ void k_prep_w(const float* __restrict__ src, int which, int K, int half, int n) {
  int i = blockIdx.x * 256 + threadIdx.x;
  if (i >= n) return;
  int col = i % K;
  float v = src[i];
  if (half && col >= half) v -= src[i - half];   // W2 - W1 fold
  u16* dst = which == 0 ? g_wm0a : which == 1 ? g_w0b : which == 2 ? g_wm1a : g_w1b;
  dst[i] = f2bf(v);
}

// ============ 256x256-tile BK=32 deep-pipelined GEMM pair ============
// 512 thr = 8 waves (2M x 4N); per-wave out 128x64 (acc[8][4] f32x4).
// LDS: 4-buffer ring (A,B: 16KB each per buf) = 128KB; 3-deep prefetch,
// counted s_waitcnt vmcnt(8) (never 0 in-loop), raw s_barrier, setprio.
// XOR chunk swizzle (both-sides): global src chunk ^= (row>>1)&3 (linear
// gl_lds dest), ds_read chunk ^= (row>>1)&3  -> bank-uniform b128 reads.

#define GEMM_PRO()                                                     \
  int t = threadIdx.x, lane = t & 63, w = t >> 6;                      \
  int chunk = gridDim.x >> 3;                                          \
  int idx = ((int)blockIdx.x & 7) * chunk + ((int)blockIdx.x >> 3);    \
  int bx = idx & ((1 << lbx) - 1), by = idx >> lbx;                    \
  int wm = w >> 2, wn = w & 3;                                         \
  int l15 = lane & 15, lq = lane >> 4;                                 \
  int gcs = (((lane & 3) ^ ((lane >> 3) & 3))) * 8;                    \
  int rA0 = w * 16 + (lane >> 2), rA1 = rA0 + 128;                     \
  int ldsA0 = w * 512, ldsA1 = 4096 + w * 512;                         \
  int ksw = (lq ^ ((l15 >> 1) & 3)) * 8;                               \
  f32x4 acc[8][4];                                                     \
  _Pragma("unroll") for (int m = 0; m < 8; m++)                        \
  _Pragma("unroll") for (int n = 0; n < 4; n++)                        \
      acc[m][n] = f32x4{0.f, 0.f, 0.f, 0.f};

#define GEMM_LOOP(STG)                                                   \
  STG(0, 0) STG(1, 1) STG(2, 2)                                          \
  asm volatile("s_waitcnt vmcnt(8)" ::: "memory");                       \
  __builtin_amdgcn_s_barrier();                                          \
  asm volatile("" ::: "memory");                                         \
  for (int ks = 0; ks < nk; ks++) {                                      \
    int b = ks & 3;                                                      \
    int kst = (ks + 3 < nk) ? ks + 3 : nk - 1;                           \
    STG(kst, (ks + 3) & 3)                                               \
    s16x8 af[8], bf[4];                                                  \
    _Pragma("unroll") for (int m = 0; m < 8; m++)                        \
        af[m] = *(const s16x8*)&As[b][(wm * 128 + m * 16 + l15) * 32 + ksw]; \
    _Pragma("unroll") for (int n = 0; n < 4; n++)                        \
        bf[n] = *(const s16x8*)&Bs[b][(wn * 64 + n * 16 + l15) * 32 + ksw];  \
    __builtin_amdgcn_s_setprio(1);                                       \
    _Pragma("unroll") for (int m = 0; m < 8; m++)                        \
    _Pragma("unroll") for (int n = 0; n < 4; n++)                        \
        acc[m][n] = mfma16x16(af[m], bf[n], acc[m][n]);                  \
    __builtin_amdgcn_s_setprio(0);                                       \
    asm volatile("s_waitcnt vmcnt(8)" ::: "memory");                     \
    __builtin_amdgcn_s_barrier();                                        \
    asm volatile("" ::: "memory");                                       \
  }

#define GEMM_STATS(si_s, si_q)                                           \
  if (t < 256) { cs[t] = 0.f; cq[t] = 0.f; }                             \
  __syncthreads();                                                       \
  _Pragma("unroll") for (int n = 0; n < 4; n++) {                        \
    float ssum = 0.f, ssq = 0.f;                                         \
    _Pragma("unroll") for (int m = 0; m < 8; m++)                        \
    _Pragma("unroll") for (int j = 0; j < 4; j++) {                      \
      float v = acc[m][n][j];                                            \
      ssum += v;                                                         \
      ssq += v * v;                                                      \
    }                                                                    \
    int col = wn * 64 + n * 16 + l15;                                    \
    atomicAdd(&cs[col], ssum);                                           \
    atomicAdd(&cq[col], ssq);                                            \
  }                                                                      \
  __syncthreads();                                                       \
  if (t < 256) {                                                         \
    atomicAdd(&S(si_s)[bx * 256 + t], cs[t]);                            \
    atomicAdd(&S(si_q)[bx * 256 + t], cq[t]);                            \
  }

// ---- gather variant: A'[row]=concat(feat[nidx[row]], feat[row>>3]), K=2C ----
__global__ __launch_bounds__(512) void k_gg8(int layer, int C, int N, int si_s,
                                             int si_q, int lbx) {
  __shared__ u16 As[4][8192];
  __shared__ u16 Bs[4][8192];
  __shared__ float cs[256], cq[256];
  const u16* feat = layer == 0 ? g_h2b : g_hl0b;
  const u16* W = layer == 0 ? g_wm0a : g_wm1a;
  GEMM_PRO();
  int K = 2 * C, nk = K >> 5;
  int RA0 = by * 256 + rA0, RA1 = RA0 + 128;
  int nb0 = g_nidx[RA0], nb1 = g_nidx[RA1];
  int ct0 = RA0 >> 3, ct1 = RA1 >> 3;
  const u16* srB0 = W + (size_t)(bx * 256 + rA0) * K + gcs;
  const u16* srB1 = W + (size_t)(bx * 256 + rA1) * K + gcs;

#define STG_G(KT, BUF)                                                        \
  {                                                                           \
    int kg_ = (KT) * 32;                                                      \
    const u16 *sa0, *sa1;                                                     \
    if (kg_ < C) {                                                            \
      sa0 = feat + (size_t)nb0 * C + kg_ + gcs;                               \
      sa1 = feat + (size_t)nb1 * C + kg_ + gcs;                               \
    } else {                                                                  \
      sa0 = feat + (size_t)ct0 * C + (kg_ - C) + gcs;                         \
      sa1 = feat + (size_t)ct1 * C + (kg_ - C) + gcs;                         \
    }                                                                         \
    gl_lds16(sa0, &As[BUF][ldsA0]);                                           \
    gl_lds16(sa1, &As[BUF][ldsA1]);                                           \
    gl_lds16(srB0 + kg_, &Bs[BUF][ldsA0]);                                    \
    gl_lds16(srB1 + kg_, &Bs[BUF][ldsA1]);                                    \
  }

  GEMM_LOOP(STG_G)
#undef STG_G

  // store Z bf16
#pragma unroll
  for (int m = 0; m < 8; m++) {
    int rbase = by * 256 + wm * 128 + m * 16 + lq * 4;
#pragma unroll
    for (int n = 0; n < 4; n++) {
      int col = bx * 256 + wn * 64 + n * 16 + l15;
#pragma unroll
      for (int j = 0; j < 4; j++)
        g_Z[(size_t)(rbase + j) * N + col] = f2bf(acc[m][n][j]);
    }
  }
  GEMM_STATS(si_s, si_q)
}

// ---- pool variant: A=g_Z, epilogue max over k=8 -> g_pooled[8192,N] ----
__global__ __launch_bounds__(512) void k_gp8(int layer, int K, int N, int si_s,
                                             int si_q, int lbx) {
  __shared__ u16 As[4][8192];
  __shared__ u16 Bs[4][8192];
  __shared__ float cs[256], cq[256];
  const u16* W = layer == 0 ? g_w0b : g_w1b;
  GEMM_PRO();
  int nk = K >> 5;
  const u16* srA0 = g_Z + (size_t)(by * 256 + rA0) * K + gcs;
  const u16* srA1 = g_Z + (size_t)(by * 256 + rA1) * K + gcs;
  const u16* srB0 = W + (size_t)(bx * 256 + rA0) * K + gcs;
  const u16* srB1 = W + (size_t)(bx * 256 + rA1) * K + gcs;

#define STG_P(KT, BUF)                                                        \
  {                                                                           \
    int kg_ = (KT) * 32;                                                      \
    gl_lds16(srA0 + kg_, &As[BUF][ldsA0]);                                    \
    gl_lds16(srA1 + kg_, &As[BUF][ldsA1]);                                    \
    gl_lds16(srB0 + kg_, &Bs[BUF][ldsA0]);                                    \
    gl_lds16(srB1 + kg_, &Bs[BUF][ldsA1]);                                    \
  }

  GEMM_LOOP(STG_P)
#undef STG_P

  // max over k=8: frag rows m*16 + lq*4 + j; pair lq 0<->1, 2<->3 via lane^16
#pragma unroll
  for (int m = 0; m < 8; m++) {
    int prow = by * 32 + wm * 16 + m * 2 + (lq >> 1);
#pragma unroll
    for (int n = 0; n < 4; n++) {
      float v4 = fmaxf(fmaxf(acc[m][n][0], acc[m][n][1]), fmaxf(acc[m][n][2], acc[m][n][3]));
      float v8 = fmaxf(v4, __shfl_xor(v4, 16, 64));
      if ((lane & 16) == 0) {
        int col = bx * 256 + wn * 64 + n * 16 + l15;
        g_pooled[(size_t)prow * N + col] = v8;
      }
    }
  }
  GEMM_STATS(si_s, si_q)
}

// ---------------- in-place bn+relu on bf16 Z ----------------
__global__ void k_bnrelu_z(int si_sc, int si_bi, int cmask, size_t n8) {
  size_t i = (size_t)blockIdx.x * 256 + threadIdx.x;
  size_t stride = (size_t)gridDim.x * 256;
  const float* sc = S(si_sc);
  const float* bi = S(si_bi);
  for (; i < n8; i += stride) {
    u16x8 v = *(const u16x8*)(g_Z + i * 8);
    int c0 = (int)((i * 8) & (size_t)cmask);
    u16x8 o;
#pragma unroll
    for (int j = 0; j < 8; j++) {
      float f = bf2f(v[j]) * sc[c0 + j] + bi[c0 + j];
      o[j] = f2bf(f > 0.f ? f : 0.f);
    }
    *(u16x8*)(g_Z + i * 8) = o;
  }
}

// ---------------- bn+relu pooled f32 -> bf16 feat (local_op 0 only) ----------------
__global__ void k_bnrelu_pool() {
  int i = blockIdx.x * 256 + threadIdx.x;  // grid 16384, n = 8192*512
  if (i >= 8192 * 512) return;
  int c = i & 511;
  float v = g_pooled[i] * S(18)[c] + S(19)[c];
  g_hl0b[i] = f2bf(v > 0.f ? v : 0.f);
}

// ---------------- final: bn+relu pooled[8192,1024] -> out (B,1024,2048) f32 ----------------
__global__ void k_final_t(float* __restrict__ out) {
  __shared__ float tile[64][65];
  int b = blockIdx.z;     // 4
  int nb = blockIdx.y;    // 32
  int cb = blockIdx.x;    // 16
  int t = threadIdx.x;
  int cl = t & 63;
  int c = cb * 64 + cl;
  float sc = S(22)[c], bi = S(23)[c];
  for (int nl = t >> 6; nl < 64; nl += 4) {
    float v = g_pooled[(size_t)(b * 2048 + nb * 64 + nl) * 1024 + c] * sc + bi;
    tile[nl][cl] = v > 0.f ? v : 0.f;
  }
  __syncthreads();
  int nl2 = t & 63;
  for (int ci = t >> 6; ci < 64; ci += 4) {
    out[((size_t)b * 1024 + cb * 64 + ci) * 2048 + nb * 64 + nl2] = tile[nl2][ci];
  }
}

extern "C" void kernel_launch(void* const* d_in, const int* in_sizes, int n_in,
                              void* d_out, int out_size, void* d_ws, size_t ws_size,
                              hipStream_t stream) {
  const float* xyz  = (const float*)d_in[0];
  const float* w_c1 = (const float*)d_in[1];
  const float* g_c1 = (const float*)d_in[2];
  const float* b_c1 = (const float*)d_in[3];
  const float* w_c2 = (const float*)d_in[4];
  const float* g_c2 = (const float*)d_in[5];
  const float* b_c2 = (const float*)d_in[6];
  const float* w_l0a = (const float*)d_in[7];
  const float* g_l0a = (const float*)d_in[8];
  const float* b_l0a = (const float*)d_in[9];
  const float* w_l0b = (const float*)d_in[10];
  const float* g_l0b = (const float*)d_in[11];
  const float* b_l0b = (const float*)d_in[12];
  const float* w_l1a = (const float*)d_in[13];
  const float* g_l1a = (const float*)d_in[14];
  const float* b_l1a = (const float*)d_in[15];
  const float* w_l1b = (const float*)d_in[16];
  const float* g_l1b = (const float*)d_in[17];
  const float* b_l1b = (const float*)d_in[18];
  float* out = (float*)d_out;

  k_zero<<<48, 256, 0, stream>>>();

  // stage 1: xyz -> 64 -> 256 (f32)
  k_lin1<<<2048, 256, 0, stream>>>(xyz, w_c1);
  k_stats<<<1, 64, 0, stream>>>(g_c1, b_c1, 0, 1, 12, 13, 1.f / 8192.f);
  k_lin2<<<512, 256, 0, stream>>>(w_c2);
  k_stats<<<4, 64, 0, stream>>>(g_c2, b_c2, 2, 3, 14, 15, 1.f / 8192.f);
  k_bnrelu_h2<<<8192, 256, 0, stream>>>();

  // kNN shared by both spa_group calls
  k_knn<<<32, 256, 0, stream>>>(xyz);

  // weight prep
  k_prep_w<<<1024, 256, 0, stream>>>(w_l0a, 0, 512, 256, 262144);
  k_prep_w<<<1024, 256, 0, stream>>>(w_l0b, 1, 512, 0, 262144);
  k_prep_w<<<4096, 256, 0, stream>>>(w_l1a, 2, 1024, 512, 1048576);
  k_prep_w<<<4096, 256, 0, stream>>>(w_l1b, 3, 1024, 0, 1048576);

  // local_op 0 (C=256 -> K=512, N=512): grid 2x256 -> 512 blocks, lbx=1
  k_gg8<<<512, 512, 0, stream>>>(0, 256, 512, 4, 5, 1);
  k_stats<<<8, 64, 0, stream>>>(g_l0a, b_l0a, 4, 5, 16, 17, 1.f / 65536.f);
  k_bnrelu_z<<<2048, 256, 0, stream>>>(16, 17, 511, (size_t)65536 * 512 / 8);
  k_gp8<<<512, 512, 0, stream>>>(0, 512, 512, 6, 7, 1);
  k_stats<<<8, 64, 0, stream>>>(g_l0b, b_l0b, 6, 7, 18, 19, 1.f / 65536.f);
  k_bnrelu_pool<<<16384, 256, 0, stream>>>();

  // local_op 1 (C=512 -> K=1024, N=1024): grid 4x256 -> 1024 blocks, lbx=2
  k_gg8<<<1024, 512, 0, stream>>>(1, 512, 1024, 8, 9, 2);
  k_stats<<<16, 64, 0, stream>>>(g_l1a, b_l1a, 8, 9, 20, 21, 1.f / 65536.f);
  k_bnrelu_z<<<2048, 256, 0, stream>>>(20, 21, 1023, (size_t)65536 * 1024 / 8);
  k_gp8<<<1024, 512, 0, stream>>>(1, 1024, 1024, 10, 11, 2);
  k_stats<<<16, 64, 0, stream>>>(g_l1b, b_l1b, 10, 11, 22, 23, 1.f / 65536.f);
  k_final_t<<<dim3(16, 32, 4), 256, 0, stream>>>(out);
}

// Round 6
// 897.555 us; speedup vs baseline: 1.4058x; 1.2511x over previous
//
#include <hip/hip_runtime.h>

typedef unsigned short u16;
typedef __attribute__((ext_vector_type(8))) short s16x8;
typedef __attribute__((ext_vector_type(8))) __bf16 bf16x8;
typedef __attribute__((ext_vector_type(8))) unsigned short u16x8;
typedef __attribute__((ext_vector_type(4))) float f32x4;

#define BN_EPS 1e-5f

// ---------- static device buffers (~187 MiB .bss; d_ws not used) ----------
__device__ u16   g_Z[(size_t)65536 * 1024];      // 128 MiB GEMM-a output (l0 uses stride 512)
__device__ float g_pooled[(size_t)8192 * 1024];  // 32 MiB pooled pre-BN
__device__ float g_h2pre[8192 * 256];            // 8 MiB
__device__ u16   g_h2b[8192 * 256];              // 4 MiB feat0 bf16
__device__ u16   g_hl0b[8192 * 512];             // 8 MiB feat1 bf16
__device__ float g_y1[8192 * 64];                // 2 MiB
__device__ u16   g_wm0a[512 * 512];              // [W1 | W2-W1] bf16
__device__ u16   g_w0b[512 * 512];
__device__ u16   g_wm1a[1024 * 1024];
__device__ u16   g_w1b[1024 * 1024];
__device__ int   g_nidx[65536];                  // global feat row of each neighbor
__device__ float g_st[24 * 1024];                // stats/scale/bias slots

#define S(i) (g_st + (i) * 1024)

static __device__ __forceinline__ float bf2f(u16 u) {
  unsigned int x = ((unsigned int)u) << 16;
  return __builtin_bit_cast(float, x);
}
static __device__ __forceinline__ u16 f2bf(float f) {
  unsigned int x = __builtin_bit_cast(unsigned int, f);
  x += 0x7fffu + ((x >> 16) & 1u);   // RNE
  return (u16)(x >> 16);
}
static __device__ __forceinline__ f32x4 mfma16x16(s16x8 a, s16x8 b, f32x4 c) {
  return __builtin_amdgcn_mfma_f32_16x16x32_bf16(
      __builtin_bit_cast(bf16x8, a), __builtin_bit_cast(bf16x8, b), c, 0, 0, 0);
}
static __device__ __forceinline__ void gl_lds16(const void* g, void* l) {
  __builtin_amdgcn_global_load_lds((const __attribute__((address_space(1))) void*)g,
                                   (__attribute__((address_space(3))) void*)l, 16, 0, 0);
}

// ---------------- zero stats accumulators ----------------
__global__ void k_zero() {
  int i = blockIdx.x * 256 + threadIdx.x;
  if (i < 12 * 1024) g_st[i] = 0.f;
}

// ---------------- stage 1a: y1[8192,64] = xyz @ w_c1^T, + channel sums ----------------
__global__ void k_lin1(const float* __restrict__ xyz, const float* __restrict__ w) {
  __shared__ float ls[64], lq[64];
  int t = threadIdx.x;
  if (t < 64) { ls[t] = 0.f; lq[t] = 0.f; }
  __syncthreads();
  int e = blockIdx.x * 256 + t;      // 8192*64, grid 2048
  int row = e >> 6, ch = e & 63;
  float x0 = xyz[row * 3], x1 = xyz[row * 3 + 1], x2 = xyz[row * 3 + 2];
  float v = x0 * w[ch * 3] + x1 * w[ch * 3 + 1] + x2 * w[ch * 3 + 2];
  g_y1[e] = v;
  atomicAdd(&ls[ch], v);
  atomicAdd(&lq[ch], v * v);
  __syncthreads();
  if (t < 64) { atomicAdd(&S(0)[t], ls[t]); atomicAdd(&S(1)[t], lq[t]); }
}

// ---------------- stats -> scale/bias ----------------
__global__ void k_stats(const float* __restrict__ g, const float* __restrict__ b,
                        int si_s, int si_q, int si_sc, int si_bi, float invcnt) {
  int c = blockIdx.x * 64 + threadIdx.x;
  float m = S(si_s)[c] * invcnt;
  float v = S(si_q)[c] * invcnt - m * m;
  float sc = g[c] * rsqrtf(v + BN_EPS);
  S(si_sc)[c] = sc;
  S(si_bi)[c] = b[c] - m * sc;
}

// ---------------- stage 1b: h2pre[8192,256] = relu(bn(y1)) @ w_c2^T ----------------
__global__ void k_lin2(const float* __restrict__ w) {
  __shared__ float hrow[64];
  int t = threadIdx.x;         // channel 0..255
  float wr[64];
#pragma unroll
  for (int i = 0; i < 64; i++) wr[i] = w[t * 64 + i];
  const float* sc1 = S(12);
  const float* bi1 = S(13);
  float ps = 0.f, pq = 0.f;
  int r0 = blockIdx.x * 16;    // grid 512
  for (int r = 0; r < 16; r++) {
    if (t < 64) {
      float v = g_y1[(r0 + r) * 64 + t];
      v = v * sc1[t] + bi1[t];
      hrow[t] = v > 0.f ? v : 0.f;
    }
    __syncthreads();
    float acc = 0.f;
#pragma unroll
    for (int i = 0; i < 64; i++) acc += hrow[i] * wr[i];
    g_h2pre[(r0 + r) * 256 + t] = acc;
    ps += acc;
    pq += acc * acc;
    __syncthreads();
  }
  atomicAdd(&S(2)[t], ps);
  atomicAdd(&S(3)[t], pq);
}

// ---------------- bn+relu f32 -> bf16 (h2pre -> h2b) ----------------
__global__ void k_bnrelu_h2() {
  int i = blockIdx.x * 256 + threadIdx.x;  // grid 8192
  if (i >= 8192 * 256) return;
  int c = i & 255;
  float v = g_h2pre[i] * S(14)[c] + S(15)[c];
  g_h2b[i] = f2bf(v > 0.f ? v : 0.f);
}

// ---------------- kNN (k=8), one WAVE per query ----------------
// grid 2048 x 256thr = 8192 waves (1/query). Lane scans 32 candidates
// (j = lane + i*64, coalesced, L2-resident), keeps sorted top-8 in regs
// (strict < insertion == top_k stable tie-break), then 8-round k-way
// merge via shfl_xor butterfly argmin on lexicographic (d, idx).
__global__ __launch_bounds__(256) void k_knn(const float* __restrict__ xyz) {
  int t = threadIdx.x, lane = t & 63, w = t >> 6;
  int qn = blockIdx.x * 4 + w;          // global query row 0..8191
  int b = qn >> 11;
  const float* xb = xyz + (size_t)b * 2048 * 3;
  int ql = qn & 2047;
  float qx = xb[ql * 3], qy = xb[ql * 3 + 1], qz = xb[ql * 3 + 2];
  float qsq = qx * qx + qy * qy + qz * qz;

  float bd[8];
  int bi[8];
#pragma unroll
  for (int i = 0; i < 8; i++) { bd[i] = 1e30f; bi[i] = 0x7fffffff; }

#pragma unroll 4
  for (int i = 0; i < 32; i++) {
    int j = lane + i * 64;
    float x = xb[j * 3], y = xb[j * 3 + 1], z = xb[j * 3 + 2];
    float sq = x * x + y * y + z * z;
    float d = qsq + sq - 2.0f * (qx * x + qy * y + qz * z);
    if (d < bd[7]) {
      bd[7] = d; bi[7] = j;
#pragma unroll
      for (int p = 7; p > 0; p--) {
        if (bd[p] < bd[p - 1]) {
          float td = bd[p]; bd[p] = bd[p - 1]; bd[p - 1] = td;
          int ti = bi[p]; bi[p] = bi[p - 1]; bi[p - 1] = ti;
        }
      }
    }
  }

  // 8-round wave merge: each round pops the global (d, idx)-min head.
  int keep = 0;
#pragma unroll
  for (int r = 0; r < 8; r++) {
    float md = bd[0];
    int mi = bi[0];
#pragma unroll
    for (int s = 1; s < 64; s <<= 1) {
      float od = __shfl_xor(md, s, 64);
      int oi = __shfl_xor(mi, s, 64);
      if (od < md || (od == md && oi < mi)) { md = od; mi = oi; }
    }
    bool own = (bd[0] == md) && (bi[0] == mi);   // bi unique -> exactly one lane
    if (own) {
#pragma unroll
      for (int p = 0; p < 7; p++) { bd[p] = bd[p + 1]; bi[p] = bi[p + 1]; }
      bd[7] = 1e30f; bi[7] = 0x7fffffff;
    }
    if (lane == r) keep = mi;
  }
  if (lane < 8) g_nidx[qn * 8 + lane] = b * 2048 + keep;
}

// ------- weight prep: which 0=wm0a(cat) 1=w0b 2=wm1a(cat) 3=w1b -------
__global__ void k_prep_w(const float* __restrict__ src, int which, int K, int half, int n) {
  int i = blockIdx.x * 256 + threadIdx.x;
  if (i >= n) return;
  int col = i % K;
  float v = src[i];
  if (half && col >= half) v -= src[i - half];   // W2 - W1 fold
  u16* dst = which == 0 ? g_wm0a : which == 1 ? g_w0b : which == 2 ? g_wm1a : g_w1b;
  dst[i] = f2bf(v);
}

// ============ 256x256-tile BK=32 deep-pipelined GEMM pair ============
// 512 thr = 8 waves (2M x 4N); per-wave out 128x64 (acc[8][4] f32x4).
// LDS: 4-buffer ring (A,B: 16KB each per buf) = 128KB; 3-deep prefetch,
// counted s_waitcnt vmcnt(8) (never 0 in-loop), raw s_barrier, setprio.
// XOR chunk swizzle (both-sides): global src chunk ^= (row>>1)&3 (linear
// gl_lds dest), ds_read chunk ^= (row>>1)&3  -> bank-uniform b128 reads.

#define GEMM_PRO()                                                     \
  int t = threadIdx.x, lane = t & 63, w = t >> 6;                      \
  int chunk = gridDim.x >> 3;                                          \
  int idx = ((int)blockIdx.x & 7) * chunk + ((int)blockIdx.x >> 3);    \
  int bx = idx & ((1 << lbx) - 1), by = idx >> lbx;                    \
  int wm = w >> 2, wn = w & 3;                                         \
  int l15 = lane & 15, lq = lane >> 4;                                 \
  int gcs = (((lane & 3) ^ ((lane >> 3) & 3))) * 8;                    \
  int rA0 = w * 16 + (lane >> 2), rA1 = rA0 + 128;                     \
  int ldsA0 = w * 512, ldsA1 = 4096 + w * 512;                         \
  int ksw = (lq ^ ((l15 >> 1) & 3)) * 8;                               \
  f32x4 acc[8][4];                                                     \
  _Pragma("unroll") for (int m = 0; m < 8; m++)                        \
  _Pragma("unroll") for (int n = 0; n < 4; n++)                        \
      acc[m][n] = f32x4{0.f, 0.f, 0.f, 0.f};

#define GEMM_LOOP(STG)                                                   \
  STG(0, 0) STG(1, 1) STG(2, 2)                                          \
  asm volatile("s_waitcnt vmcnt(8)" ::: "memory");                       \
  __builtin_amdgcn_s_barrier();                                          \
  asm volatile("" ::: "memory");                                         \
  for (int ks = 0; ks < nk; ks++) {                                      \
    int b = ks & 3;                                                      \
    int kst = (ks + 3 < nk) ? ks + 3 : nk - 1;                           \
    STG(kst, (ks + 3) & 3)                                               \
    s16x8 af[8], bf[4];                                                  \
    _Pragma("unroll") for (int m = 0; m < 8; m++)                        \
        af[m] = *(const s16x8*)&As[b][(wm * 128 + m * 16 + l15) * 32 + ksw]; \
    _Pragma("unroll") for (int n = 0; n < 4; n++)                        \
        bf[n] = *(const s16x8*)&Bs[b][(wn * 64 + n * 16 + l15) * 32 + ksw];  \
    __builtin_amdgcn_s_setprio(1);                                       \
    _Pragma("unroll") for (int m = 0; m < 8; m++)                        \
    _Pragma("unroll") for (int n = 0; n < 4; n++)                        \
        acc[m][n] = mfma16x16(af[m], bf[n], acc[m][n]);                  \
    __builtin_amdgcn_s_setprio(0);                                       \
    asm volatile("s_waitcnt vmcnt(8)" ::: "memory");                     \
    __builtin_amdgcn_s_barrier();                                        \
    asm volatile("" ::: "memory");                                       \
  }

#define GEMM_STATS(si_s, si_q)                                           \
  if (t < 256) { cs[t] = 0.f; cq[t] = 0.f; }                             \
  __syncthreads();                                                       \
  _Pragma("unroll") for (int n = 0; n < 4; n++) {                        \
    float ssum = 0.f, ssq = 0.f;                                         \
    _Pragma("unroll") for (int m = 0; m < 8; m++)                        \
    _Pragma("unroll") for (int j = 0; j < 4; j++) {                      \
      float v = acc[m][n][j];                                            \
      ssum += v;                                                         \
      ssq += v * v;                                                      \
    }                                                                    \
    int col = wn * 64 + n * 16 + l15;                                    \
    atomicAdd(&cs[col], ssum);                                           \
    atomicAdd(&cq[col], ssq);                                            \
  }                                                                      \
  __syncthreads();                                                       \
  if (t < 256) {                                                         \
    atomicAdd(&S(si_s)[bx * 256 + t], cs[t]);                            \
    atomicAdd(&S(si_q)[bx * 256 + t], cq[t]);                            \
  }

// ---- gather variant: A'[row]=concat(feat[nidx[row]], feat[row>>3]), K=2C ----
__global__ __launch_bounds__(512) void k_gg8(int layer, int C, int N, int si_s,
                                             int si_q, int lbx) {
  __shared__ u16 As[4][8192];
  __shared__ u16 Bs[4][8192];
  __shared__ float cs[256], cq[256];
  const u16* feat = layer == 0 ? g_h2b : g_hl0b;
  const u16* W = layer == 0 ? g_wm0a : g_wm1a;
  GEMM_PRO();
  int K = 2 * C, nk = K >> 5;
  int RA0 = by * 256 + rA0, RA1 = RA0 + 128;
  int nb0 = g_nidx[RA0], nb1 = g_nidx[RA1];
  int ct0 = RA0 >> 3, ct1 = RA1 >> 3;
  const u16* srB0 = W + (size_t)(bx * 256 + rA0) * K + gcs;
  const u16* srB1 = W + (size_t)(bx * 256 + rA1) * K + gcs;

#define STG_G(KT, BUF)                                                        \
  {                                                                           \
    int kg_ = (KT) * 32;                                                      \
    const u16 *sa0, *sa1;                                                     \
    if (kg_ < C) {                                                            \
      sa0 = feat + (size_t)nb0 * C + kg_ + gcs;                               \
      sa1 = feat + (size_t)nb1 * C + kg_ + gcs;                               \
    } else {                                                                  \
      sa0 = feat + (size_t)ct0 * C + (kg_ - C) + gcs;                         \
      sa1 = feat + (size_t)ct1 * C + (kg_ - C) + gcs;                         \
    }                                                                         \
    gl_lds16(sa0, &As[BUF][ldsA0]);                                           \
    gl_lds16(sa1, &As[BUF][ldsA1]);                                           \
    gl_lds16(srB0 + kg_, &Bs[BUF][ldsA0]);                                    \
    gl_lds16(srB1 + kg_, &Bs[BUF][ldsA1]);                                    \
  }

  GEMM_LOOP(STG_G)
#undef STG_G

  // store Z bf16
#pragma unroll
  for (int m = 0; m < 8; m++) {
    int rbase = by * 256 + wm * 128 + m * 16 + lq * 4;
#pragma unroll
    for (int n = 0; n < 4; n++) {
      int col = bx * 256 + wn * 64 + n * 16 + l15;
#pragma unroll
      for (int j = 0; j < 4; j++)
        g_Z[(size_t)(rbase + j) * N + col] = f2bf(acc[m][n][j]);
    }
  }
  GEMM_STATS(si_s, si_q)
}

// ---- pool variant: A=g_Z, epilogue max over k=8 -> g_pooled[8192,N] ----
__global__ __launch_bounds__(512) void k_gp8(int layer, int K, int N, int si_s,
                                             int si_q, int lbx) {
  __shared__ u16 As[4][8192];
  __shared__ u16 Bs[4][8192];
  __shared__ float cs[256], cq[256];
  const u16* W = layer == 0 ? g_w0b : g_w1b;
  GEMM_PRO();
  int nk = K >> 5;
  const u16* srA0 = g_Z + (size_t)(by * 256 + rA0) * K + gcs;
  const u16* srA1 = g_Z + (size_t)(by * 256 + rA1) * K + gcs;
  const u16* srB0 = W + (size_t)(bx * 256 + rA0) * K + gcs;
  const u16* srB1 = W + (size_t)(bx * 256 + rA1) * K + gcs;

#define STG_P(KT, BUF)                                                        \
  {                                                                           \
    int kg_ = (KT) * 32;                                                      \
    gl_lds16(srA0 + kg_, &As[BUF][ldsA0]);                                    \
    gl_lds16(srA1 + kg_, &As[BUF][ldsA1]);                                    \
    gl_lds16(srB0 + kg_, &Bs[BUF][ldsA0]);                                    \
    gl_lds16(srB1 + kg_, &Bs[BUF][ldsA1]);                                    \
  }

  GEMM_LOOP(STG_P)
#undef STG_P

  // max over k=8: frag rows m*16 + lq*4 + j; pair lq 0<->1, 2<->3 via lane^16
#pragma unroll
  for (int m = 0; m < 8; m++) {
    int prow = by * 32 + wm * 16 + m * 2 + (lq >> 1);
#pragma unroll
    for (int n = 0; n < 4; n++) {
      float v4 = fmaxf(fmaxf(acc[m][n][0], acc[m][n][1]), fmaxf(acc[m][n][2], acc[m][n][3]));
      float v8 = fmaxf(v4, __shfl_xor(v4, 16, 64));
      if ((lane & 16) == 0) {
        int col = bx * 256 + wn * 64 + n * 16 + l15;
        g_pooled[(size_t)prow * N + col] = v8;
      }
    }
  }
  GEMM_STATS(si_s, si_q)
}

// ---------------- in-place bn+relu on bf16 Z ----------------
__global__ void k_bnrelu_z(int si_sc, int si_bi, int cmask, size_t n8) {
  size_t i = (size_t)blockIdx.x * 256 + threadIdx.x;
  size_t stride = (size_t)gridDim.x * 256;
  const float* sc = S(si_sc);
  const float* bi = S(si_bi);
  for (; i < n8; i += stride) {
    u16x8 v = *(const u16x8*)(g_Z + i * 8);
    int c0 = (int)((i * 8) & (size_t)cmask);
    u16x8 o;
#pragma unroll
    for (int j = 0; j < 8; j++) {
      float f = bf2f(v[j]) * sc[c0 + j] + bi[c0 + j];
      o[j] = f2bf(f > 0.f ? f : 0.f);
    }
    *(u16x8*)(g_Z + i * 8) = o;
  }
}

// ---------------- bn+relu pooled f32 -> bf16 feat (local_op 0 only) ----------------
__global__ void k_bnrelu_pool() {
  int i = blockIdx.x * 256 + threadIdx.x;  // grid 16384, n = 8192*512
  if (i >= 8192 * 512) return;
  int c = i & 511;
  float v = g_pooled[i] * S(18)[c] + S(19)[c];
  g_hl0b[i] = f2bf(v > 0.f ? v : 0.f);
}

// ---------------- final: bn+relu pooled[8192,1024] -> out (B,1024,2048) f32 ----------------
__global__ void k_final_t(float* __restrict__ out) {
  __shared__ float tile[64][65];
  int b = blockIdx.z;     // 4
  int nb = blockIdx.y;    // 32
  int cb = blockIdx.x;    // 16
  int t = threadIdx.x;
  int cl = t & 63;
  int c = cb * 64 + cl;
  float sc = S(22)[c], bi = S(23)[c];
  for (int nl = t >> 6; nl < 64; nl += 4) {
    float v = g_pooled[(size_t)(b * 2048 + nb * 64 + nl) * 1024 + c] * sc + bi;
    tile[nl][cl] = v > 0.f ? v : 0.f;
  }
  __syncthreads();
  int nl2 = t & 63;
  for (int ci = t >> 6; ci < 64; ci += 4) {
    out[((size_t)b * 1024 + cb * 64 + ci) * 2048 + nb * 64 + nl2] = tile[nl2][ci];
  }
}

extern "C" void kernel_launch(void* const* d_in, const int* in_sizes, int n_in,
                              void* d_out, int out_size, void* d_ws, size_t ws_size,
                              hipStream_t stream) {
  const float* xyz  = (const float*)d_in[0];
  const float* w_c1 = (const float*)d_in[1];
  const float* g_c1 = (const float*)d_in[2];
  const float* b_c1 = (const float*)d_in[3];
  const float* w_c2 = (const float*)d_in[4];
  const float* g_c2 = (const float*)d_in[5];
  const float* b_c2 = (const float*)d_in[6];
  const float* w_l0a = (const float*)d_in[7];
  const float* g_l0a = (const float*)d_in[8];
  const float* b_l0a = (const float*)d_in[9];
  const float* w_l0b = (const float*)d_in[10];
  const float* g_l0b = (const float*)d_in[11];
  const float* b_l0b = (const float*)d_in[12];
  const float* w_l1a = (const float*)d_in[13];
  const float* g_l1a = (const float*)d_in[14];
  const float* b_l1a = (const float*)d_in[15];
  const float* w_l1b = (const float*)d_in[16];
  const float* g_l1b = (const float*)d_in[17];
  const float* b_l1b = (const float*)d_in[18];
  float* out = (float*)d_out;

  k_zero<<<48, 256, 0, stream>>>();

  // stage 1: xyz -> 64 -> 256 (f32)
  k_lin1<<<2048, 256, 0, stream>>>(xyz, w_c1);
  k_stats<<<1, 64, 0, stream>>>(g_c1, b_c1, 0, 1, 12, 13, 1.f / 8192.f);
  k_lin2<<<512, 256, 0, stream>>>(w_c2);
  k_stats<<<4, 64, 0, stream>>>(g_c2, b_c2, 2, 3, 14, 15, 1.f / 8192.f);
  k_bnrelu_h2<<<8192, 256, 0, stream>>>();

  // kNN shared by both spa_group calls: 1 wave/query, 8192 waves
  k_knn<<<2048, 256, 0, stream>>>(xyz);

  // weight prep
  k_prep_w<<<1024, 256, 0, stream>>>(w_l0a, 0, 512, 256, 262144);
  k_prep_w<<<1024, 256, 0, stream>>>(w_l0b, 1, 512, 0, 262144);
  k_prep_w<<<4096, 256, 0, stream>>>(w_l1a, 2, 1024, 512, 1048576);
  k_prep_w<<<4096, 256, 0, stream>>>(w_l1b, 3, 1024, 0, 1048576);

  // local_op 0 (C=256 -> K=512, N=512): grid 2x256 -> 512 blocks, lbx=1
  k_gg8<<<512, 512, 0, stream>>>(0, 256, 512, 4, 5, 1);
  k_stats<<<8, 64, 0, stream>>>(g_l0a, b_l0a, 4, 5, 16, 17, 1.f / 65536.f);
  k_bnrelu_z<<<2048, 256, 0, stream>>>(16, 17, 511, (size_t)65536 * 512 / 8);
  k_gp8<<<512, 512, 0, stream>>>(0, 512, 512, 6, 7, 1);
  k_stats<<<8, 64, 0, stream>>>(g_l0b, b_l0b, 6, 7, 18, 19, 1.f / 65536.f);
  k_bnrelu_pool<<<16384, 256, 0, stream>>>();

  // local_op 1 (C=512 -> K=1024, N=1024): grid 4x256 -> 1024 blocks, lbx=2
  k_gg8<<<1024, 512, 0, stream>>>(1, 512, 1024, 8, 9, 2);
  k_stats<<<16, 64, 0, stream>>>(g_l1a, b_l1a, 8, 9, 20, 21, 1.f / 65536.f);
  k_bnrelu_z<<<2048, 256, 0, stream>>>(20, 21, 1023, (size_t)65536 * 1024 / 8);
  k_gp8<<<1024, 512, 0, stream>>>(1, 1024, 1024, 10, 11, 2);
  k_stats<<<16, 64, 0, stream>>>(g_l1b, b_l1b, 10, 11, 22, 23, 1.f / 65536.f);
  k_final_t<<<dim3(16, 32, 4), 256, 0, stream>>>(out);
}

// Round 7
// 773.424 us; speedup vs baseline: 1.6314x; 1.1605x over previous
//
#include <hip/hip_runtime.h>

typedef unsigned short u16;
typedef __attribute__((ext_vector_type(8))) short s16x8;
typedef __attribute__((ext_vector_type(8))) __bf16 bf16x8;
typedef __attribute__((ext_vector_type(8))) unsigned short u16x8;
typedef __attribute__((ext_vector_type(4))) float f32x4;

#define BN_EPS 1e-5f

// ---------- static device buffers (~219 MiB .bss; d_ws not used) ----------
__device__ u16   g_Z[(size_t)65536 * 1024];      // 128 MiB combined A for GEMM-b
__device__ u16   g_F[(size_t)8192 * 2048];       // 32 MiB  F = feat @ [W1 ; W2-W1]^T
__device__ float g_pooled[(size_t)8192 * 1024];  // 32 MiB pooled pre-BN
__device__ float g_h2pre[8192 * 256];            // 8 MiB
__device__ u16   g_h2b[8192 * 256];              // 4 MiB feat0 bf16
__device__ u16   g_hl0b[8192 * 512];             // 8 MiB feat1 bf16
__device__ float g_y1[8192 * 64];                // 2 MiB
__device__ u16   g_wm0a[1024 * 256];             // stacked [W1 ; W2-W1] l0
__device__ u16   g_w0b[512 * 512];
__device__ u16   g_wm1a[2048 * 512];             // stacked l1
__device__ u16   g_w1b[1024 * 1024];
__device__ int   g_nidx[65536];                  // global feat row of each neighbor
__device__ float g_st[24 * 1024];                // stats/scale/bias slots

#define S(i) (g_st + (i) * 1024)

static __device__ __forceinline__ float bf2f(u16 u) {
  unsigned int x = ((unsigned int)u) << 16;
  return __builtin_bit_cast(float, x);
}
static __device__ __forceinline__ u16 f2bf(float f) {
  unsigned int x = __builtin_bit_cast(unsigned int, f);
  x += 0x7fffu + ((x >> 16) & 1u);   // RNE
  return (u16)(x >> 16);
}
static __device__ __forceinline__ f32x4 mfma16x16(s16x8 a, s16x8 b, f32x4 c) {
  return __builtin_amdgcn_mfma_f32_16x16x32_bf16(
      __builtin_bit_cast(bf16x8, a), __builtin_bit_cast(bf16x8, b), c, 0, 0, 0);
}
static __device__ __forceinline__ void gl_lds16(const void* g, void* l) {
  __builtin_amdgcn_global_load_lds((const __attribute__((address_space(1))) void*)g,
                                   (__attribute__((address_space(3))) void*)l, 16, 0, 0);
}

// ---------------- zero stats accumulators ----------------
__global__ void k_zero() {
  int i = blockIdx.x * 256 + threadIdx.x;
  if (i < 12 * 1024) g_st[i] = 0.f;
}

// ---------------- stage 1a: y1[8192,64] = xyz @ w_c1^T, + channel sums ----------------
__global__ void k_lin1(const float* __restrict__ xyz, const float* __restrict__ w) {
  __shared__ float ls[64], lq[64];
  int t = threadIdx.x;
  if (t < 64) { ls[t] = 0.f; lq[t] = 0.f; }
  __syncthreads();
  int e = blockIdx.x * 256 + t;      // 8192*64, grid 2048
  int row = e >> 6, ch = e & 63;
  float x0 = xyz[row * 3], x1 = xyz[row * 3 + 1], x2 = xyz[row * 3 + 2];
  float v = x0 * w[ch * 3] + x1 * w[ch * 3 + 1] + x2 * w[ch * 3 + 2];
  g_y1[e] = v;
  atomicAdd(&ls[ch], v);
  atomicAdd(&lq[ch], v * v);
  __syncthreads();
  if (t < 64) { atomicAdd(&S(0)[t], ls[t]); atomicAdd(&S(1)[t], lq[t]); }
}

// ---------------- stats -> scale/bias ----------------
__global__ void k_stats(const float* __restrict__ g, const float* __restrict__ b,
                        int si_s, int si_q, int si_sc, int si_bi, float invcnt) {
  int c = blockIdx.x * 64 + threadIdx.x;
  float m = S(si_s)[c] * invcnt;
  float v = S(si_q)[c] * invcnt - m * m;
  float sc = g[c] * rsqrtf(v + BN_EPS);
  S(si_sc)[c] = sc;
  S(si_bi)[c] = b[c] - m * sc;
}

// ---------------- stage 1b: h2pre[8192,256] = relu(bn(y1)) @ w_c2^T ----------------
__global__ void k_lin2(const float* __restrict__ w) {
  __shared__ float hrow[64];
  int t = threadIdx.x;         // channel 0..255
  float wr[64];
#pragma unroll
  for (int i = 0; i < 64; i++) wr[i] = w[t * 64 + i];
  const float* sc1 = S(12);
  const float* bi1 = S(13);
  float ps = 0.f, pq = 0.f;
  int r0 = blockIdx.x * 16;    // grid 512
  for (int r = 0; r < 16; r++) {
    if (t < 64) {
      float v = g_y1[(r0 + r) * 64 + t];
      v = v * sc1[t] + bi1[t];
      hrow[t] = v > 0.f ? v : 0.f;
    }
    __syncthreads();
    float acc = 0.f;
#pragma unroll
    for (int i = 0; i < 64; i++) acc += hrow[i] * wr[i];
    g_h2pre[(r0 + r) * 256 + t] = acc;
    ps += acc;
    pq += acc * acc;
    __syncthreads();
  }
  atomicAdd(&S(2)[t], ps);
  atomicAdd(&S(3)[t], pq);
}

// ---------------- bn+relu f32 -> bf16 (h2pre -> h2b) ----------------
__global__ void k_bnrelu_h2() {
  int i = blockIdx.x * 256 + threadIdx.x;  // grid 8192
  if (i >= 8192 * 256) return;
  int c = i & 255;
  float v = g_h2pre[i] * S(14)[c] + S(15)[c];
  g_h2b[i] = f2bf(v > 0.f ? v : 0.f);
}

// ---------------- kNN (k=8), one WAVE per query ----------------
__global__ __launch_bounds__(256) void k_knn(const float* __restrict__ xyz) {
  int t = threadIdx.x, lane = t & 63, w = t >> 6;
  int qn = blockIdx.x * 4 + w;          // global query row 0..8191
  int b = qn >> 11;
  const float* xb = xyz + (size_t)b * 2048 * 3;
  int ql = qn & 2047;
  float qx = xb[ql * 3], qy = xb[ql * 3 + 1], qz = xb[ql * 3 + 2];
  float qsq = qx * qx + qy * qy + qz * qz;

  float bd[8];
  int bi[8];
#pragma unroll
  for (int i = 0; i < 8; i++) { bd[i] = 1e30f; bi[i] = 0x7fffffff; }

#pragma unroll 4
  for (int i = 0; i < 32; i++) {
    int j = lane + i * 64;
    float x = xb[j * 3], y = xb[j * 3 + 1], z = xb[j * 3 + 2];
    float sq = x * x + y * y + z * z;
    float d = qsq + sq - 2.0f * (qx * x + qy * y + qz * z);
    if (d < bd[7]) {
      bd[7] = d; bi[7] = j;
#pragma unroll
      for (int p = 7; p > 0; p--) {
        if (bd[p] < bd[p - 1]) {
          float td = bd[p]; bd[p] = bd[p - 1]; bd[p - 1] = td;
          int ti = bi[p]; bi[p] = bi[p - 1]; bi[p - 1] = ti;
        }
      }
    }
  }

  // 8-round wave merge: pop global (d, idx)-min each round.
  int keep = 0;
#pragma unroll
  for (int r = 0; r < 8; r++) {
    float md = bd[0];
    int mi = bi[0];
#pragma unroll
    for (int s = 1; s < 64; s <<= 1) {
      float od = __shfl_xor(md, s, 64);
      int oi = __shfl_xor(mi, s, 64);
      if (od < md || (od == md && oi < mi)) { md = od; mi = oi; }
    }
    bool own = (bd[0] == md) && (bi[0] == mi);
    if (own) {
#pragma unroll
      for (int p = 0; p < 7; p++) { bd[p] = bd[p + 1]; bi[p] = bi[p + 1]; }
      bd[7] = 1e30f; bi[7] = 0x7fffffff;
    }
    if (lane == r) keep = mi;
  }
  if (lane < 8) g_nidx[qn * 8 + lane] = b * 2048 + keep;
}

// ------- plain weight bf16 prep: which 1=w0b 3=w1b -------
__global__ void k_prep_w(const float* __restrict__ src, int which, int n) {
  int i = blockIdx.x * 256 + threadIdx.x;
  if (i >= n) return;
  u16* dst = which == 1 ? g_w0b : g_w1b;
  dst[i] = f2bf(src[i]);
}

// ------- stacked weight prep: Wst[2N, C]: rows [0,N)=W1, [N,2N)=W2-W1 -------
// src is [N, 2C]; which 0=g_wm0a 2=g_wm1a; lc = log2(C)
__global__ void k_prep_wst(const float* __restrict__ src, int which, int lc, int N, int n) {
  int i = blockIdx.x * 256 + threadIdx.x;
  if (i >= n) return;
  int C = 1 << lc;
  int r = i >> lc, c = i & (C - 1);
  float v;
  if (r < N) v = src[r * 2 * C + c];
  else { int o = r - N; v = src[o * 2 * C + C + c] - src[o * 2 * C + c]; }
  u16* dst = which == 0 ? g_wm0a : g_wm1a;
  dst[i] = f2bf(v);
}

// ============ 256x256-tile BK=32 deep-pipelined GEMM core ============
// 512 thr = 8 waves (2M x 4N); per-wave out 128x64 (acc[8][4] f32x4).
// 4-buffer LDS ring, 3-deep prefetch, counted vmcnt(8), raw s_barrier, setprio.
// XOR chunk swizzle both-sides (bank conflicts measured 0).

#define GEMM_PRO()                                                     \
  int t = threadIdx.x, lane = t & 63, w = t >> 6;                      \
  int chunk = gridDim.x >> 3;                                          \
  int idx = ((int)blockIdx.x & 7) * chunk + ((int)blockIdx.x >> 3);    \
  int bx = idx & ((1 << lbx) - 1), by = idx >> lbx;                    \
  int wm = w >> 2, wn = w & 3;                                         \
  int l15 = lane & 15, lq = lane >> 4;                                 \
  int gcs = (((lane & 3) ^ ((lane >> 3) & 3))) * 8;                    \
  int rA0 = w * 16 + (lane >> 2), rA1 = rA0 + 128;                     \
  int ldsA0 = w * 512, ldsA1 = 4096 + w * 512;                         \
  int ksw = (lq ^ ((l15 >> 1) & 3)) * 8;                               \
  f32x4 acc[8][4];                                                     \
  _Pragma("unroll") for (int m = 0; m < 8; m++)                        \
  _Pragma("unroll") for (int n = 0; n < 4; n++)                        \
      acc[m][n] = f32x4{0.f, 0.f, 0.f, 0.f};

#define GEMM_LOOP(STG)                                                   \
  STG(0, 0) STG(1, 1) STG(2, 2)                                          \
  asm volatile("s_waitcnt vmcnt(8)" ::: "memory");                       \
  __builtin_amdgcn_s_barrier();                                          \
  asm volatile("" ::: "memory");                                         \
  for (int ks = 0; ks < nk; ks++) {                                      \
    int b = ks & 3;                                                      \
    int kst = (ks + 3 < nk) ? ks + 3 : nk - 1;                           \
    STG(kst, (ks + 3) & 3)                                               \
    s16x8 af[8], bf[4];                                                  \
    _Pragma("unroll") for (int m = 0; m < 8; m++)                        \
        af[m] = *(const s16x8*)&As[b][(wm * 128 + m * 16 + l15) * 32 + ksw]; \
    _Pragma("unroll") for (int n = 0; n < 4; n++)                        \
        bf[n] = *(const s16x8*)&Bs[b][(wn * 64 + n * 16 + l15) * 32 + ksw];  \
    __builtin_amdgcn_s_setprio(1);                                       \
    _Pragma("unroll") for (int m = 0; m < 8; m++)                        \
    _Pragma("unroll") for (int n = 0; n < 4; n++)                        \
        acc[m][n] = mfma16x16(af[m], bf[n], acc[m][n]);                  \
    __builtin_amdgcn_s_setprio(0);                                       \
    asm volatile("s_waitcnt vmcnt(8)" ::: "memory");                     \
    __builtin_amdgcn_s_barrier();                                        \
    asm volatile("" ::: "memory");                                       \
  }

#define GEMM_STATS(si_s, si_q)                                           \
  if (t < 256) { cs[t] = 0.f; cq[t] = 0.f; }                             \
  __syncthreads();                                                       \
  _Pragma("unroll") for (int n = 0; n < 4; n++) {                        \
    float ssum = 0.f, ssq = 0.f;                                         \
    _Pragma("unroll") for (int m = 0; m < 8; m++)                        \
    _Pragma("unroll") for (int j = 0; j < 4; j++) {                      \
      float v = acc[m][n][j];                                            \
      ssum += v;                                                         \
      ssq += v * v;                                                      \
    }                                                                    \
    int col = wn * 64 + n * 16 + l15;                                    \
    atomicAdd(&cs[col], ssum);                                           \
    atomicAdd(&cq[col], ssq);                                            \
  }                                                                      \
  __syncthreads();                                                       \
  if (t < 256) {                                                         \
    atomicAdd(&S(si_s)[bx * 256 + t], cs[t]);                            \
    atomicAdd(&S(si_q)[bx * 256 + t], cq[t]);                            \
  }

// ---- F-GEMM: F[8192, N2] = feat[8192, C] @ Wst[N2, C]^T (no stats) ----
__global__ __launch_bounds__(512) void k_fgemm(int layer, int C, int N2, int lbx) {
  __shared__ u16 As[4][8192];
  __shared__ u16 Bs[4][8192];
  const u16* feat = layer == 0 ? g_h2b : g_hl0b;
  const u16* W = layer == 0 ? g_wm0a : g_wm1a;
  GEMM_PRO();
  int nk = C >> 5;
  const u16* srA0 = feat + (size_t)(by * 256 + rA0) * C + gcs;
  const u16* srA1 = feat + (size_t)(by * 256 + rA1) * C + gcs;
  const u16* srB0 = W + (size_t)(bx * 256 + rA0) * C + gcs;
  const u16* srB1 = W + (size_t)(bx * 256 + rA1) * C + gcs;

#define STG_F(KT, BUF)                                                        \
  {                                                                           \
    int kg_ = (KT) * 32;                                                      \
    gl_lds16(srA0 + kg_, &As[BUF][ldsA0]);                                    \
    gl_lds16(srA1 + kg_, &As[BUF][ldsA1]);                                    \
    gl_lds16(srB0 + kg_, &Bs[BUF][ldsA0]);                                    \
    gl_lds16(srB1 + kg_, &Bs[BUF][ldsA1]);                                    \
  }

  GEMM_LOOP(STG_F)
#undef STG_F

#pragma unroll
  for (int m = 0; m < 8; m++) {
    int rbase = by * 256 + wm * 128 + m * 16 + lq * 4;
#pragma unroll
    for (int n = 0; n < 4; n++) {
      int col = bx * 256 + wn * 64 + n * 16 + l15;
#pragma unroll
      for (int j = 0; j < 4; j++)
        g_F[(size_t)(rbase + j) * N2 + col] = f2bf(acc[m][n][j]);
    }
  }
}

// ---- combine: Z[row,c] = F[nidx[row], c] + F[row>>3, N+c]; + channel stats ----
// 256 blocks x 512 thr; thread owns 8 fixed channels across its row range.
__global__ __launch_bounds__(512) void k_combine(int N, int lgc, int si_s, int si_q) {
  __shared__ float Ls[1024], Lq[1024];
  int t = threadIdx.x;
  int chs8 = 1 << lgc;               // threads per row-slice (N/8)
  int c8 = t & (chs8 - 1);
  int g = t >> lgc;
  int G = 512 >> lgc;                // row groups per block
  int rpg = 256 / G;
  int row0 = blockIdx.x * 256 + g * rpg;
  int ch0 = c8 * 8;
  int N2 = 2 * N;
  float ss[8], sq[8];
#pragma unroll
  for (int j = 0; j < 8; j++) { ss[j] = 0.f; sq[j] = 0.f; }

  for (int r = row0; r < row0 + rpg; r++) {
    int nb = g_nidx[r];
    int ct = r >> 3;
    u16x8 a = *(const u16x8*)(g_F + (size_t)nb * N2 + ch0);
    u16x8 b = *(const u16x8*)(g_F + (size_t)ct * N2 + N + ch0);
    u16x8 o;
#pragma unroll
    for (int j = 0; j < 8; j++) {
      float z = bf2f(a[j]) + bf2f(b[j]);
      o[j] = f2bf(z);
      ss[j] += z;
      sq[j] += z * z;
    }
    *(u16x8*)(g_Z + (size_t)r * N + ch0) = o;
  }

  for (int c = t; c < N; c += 512) { Ls[c] = 0.f; Lq[c] = 0.f; }
  __syncthreads();
#pragma unroll
  for (int j = 0; j < 8; j++) {
    atomicAdd(&Ls[ch0 + j], ss[j]);
    atomicAdd(&Lq[ch0 + j], sq[j]);
  }
  __syncthreads();
  for (int c = t; c < N; c += 512) {
    atomicAdd(&S(si_s)[c], Ls[c]);
    atomicAdd(&S(si_q)[c], Lq[c]);
  }
}

// ---- pool GEMM: A=g_Z, epilogue max over k=8 -> g_pooled[8192,N] + stats ----
__global__ __launch_bounds__(512) void k_gp8(int layer, int K, int N, int si_s,
                                             int si_q, int lbx) {
  __shared__ u16 As[4][8192];
  __shared__ u16 Bs[4][8192];
  __shared__ float cs[256], cq[256];
  const u16* W = layer == 0 ? g_w0b : g_w1b;
  GEMM_PRO();
  int nk = K >> 5;
  const u16* srA0 = g_Z + (size_t)(by * 256 + rA0) * K + gcs;
  const u16* srA1 = g_Z + (size_t)(by * 256 + rA1) * K + gcs;
  const u16* srB0 = W + (size_t)(bx * 256 + rA0) * K + gcs;
  const u16* srB1 = W + (size_t)(bx * 256 + rA1) * K + gcs;

#define STG_P(KT, BUF)                                                        \
  {                                                                           \
    int kg_ = (KT) * 32;                                                      \
    gl_lds16(srA0 + kg_, &As[BUF][ldsA0]);                                    \
    gl_lds16(srA1 + kg_, &As[BUF][ldsA1]);                                    \
    gl_lds16(srB0 + kg_, &Bs[BUF][ldsA0]);                                    \
    gl_lds16(srB1 + kg_, &Bs[BUF][ldsA1]);                                    \
  }

  GEMM_LOOP(STG_P)
#undef STG_P

  // max over k=8: frag rows m*16 + lq*4 + j; pair lq 0<->1, 2<->3 via lane^16
#pragma unroll
  for (int m = 0; m < 8; m++) {
    int prow = by * 32 + wm * 16 + m * 2 + (lq >> 1);
#pragma unroll
    for (int n = 0; n < 4; n++) {
      float v4 = fmaxf(fmaxf(acc[m][n][0], acc[m][n][1]), fmaxf(acc[m][n][2], acc[m][n][3]));
      float v8 = fmaxf(v4, __shfl_xor(v4, 16, 64));
      if ((lane & 16) == 0) {
        int col = bx * 256 + wn * 64 + n * 16 + l15;
        g_pooled[(size_t)prow * N + col] = v8;
      }
    }
  }
  GEMM_STATS(si_s, si_q)
}

// ---------------- in-place bn+relu on bf16 Z ----------------
__global__ void k_bnrelu_z(int si_sc, int si_bi, int cmask, size_t n8) {
  size_t i = (size_t)blockIdx.x * 256 + threadIdx.x;
  size_t stride = (size_t)gridDim.x * 256;
  const float* sc = S(si_sc);
  const float* bi = S(si_bi);
  for (; i < n8; i += stride) {
    u16x8 v = *(const u16x8*)(g_Z + i * 8);
    int c0 = (int)((i * 8) & (size_t)cmask);
    u16x8 o;
#pragma unroll
    for (int j = 0; j < 8; j++) {
      float f = bf2f(v[j]) * sc[c0 + j] + bi[c0 + j];
      o[j] = f2bf(f > 0.f ? f : 0.f);
    }
    *(u16x8*)(g_Z + i * 8) = o;
  }
}

// ---------------- bn+relu pooled f32 -> bf16 feat (local_op 0 only) ----------------
__global__ void k_bnrelu_pool() {
  int i = blockIdx.x * 256 + threadIdx.x;  // grid 16384, n = 8192*512
  if (i >= 8192 * 512) return;
  int c = i & 511;
  float v = g_pooled[i] * S(18)[c] + S(19)[c];
  g_hl0b[i] = f2bf(v > 0.f ? v : 0.f);
}

// ---------------- final: bn+relu pooled[8192,1024] -> out (B,1024,2048) f32 ----------------
__global__ void k_final_t(float* __restrict__ out) {
  __shared__ float tile[64][65];
  int b = blockIdx.z;     // 4
  int nb = blockIdx.y;    // 32
  int cb = blockIdx.x;    // 16
  int t = threadIdx.x;
  int cl = t & 63;
  int c = cb * 64 + cl;
  float sc = S(22)[c], bi = S(23)[c];
  for (int nl = t >> 6; nl < 64; nl += 4) {
    float v = g_pooled[(size_t)(b * 2048 + nb * 64 + nl) * 1024 + c] * sc + bi;
    tile[nl][cl] = v > 0.f ? v : 0.f;
  }
  __syncthreads();
  int nl2 = t & 63;
  for (int ci = t >> 6; ci < 64; ci += 4) {
    out[((size_t)b * 1024 + cb * 64 + ci) * 2048 + nb * 64 + nl2] = tile[nl2][ci];
  }
}

extern "C" void kernel_launch(void* const* d_in, const int* in_sizes, int n_in,
                              void* d_out, int out_size, void* d_ws, size_t ws_size,
                              hipStream_t stream) {
  const float* xyz  = (const float*)d_in[0];
  const float* w_c1 = (const float*)d_in[1];
  const float* g_c1 = (const float*)d_in[2];
  const float* b_c1 = (const float*)d_in[3];
  const float* w_c2 = (const float*)d_in[4];
  const float* g_c2 = (const float*)d_in[5];
  const float* b_c2 = (const float*)d_in[6];
  const float* w_l0a = (const float*)d_in[7];
  const float* g_l0a = (const float*)d_in[8];
  const float* b_l0a = (const float*)d_in[9];
  const float* w_l0b = (const float*)d_in[10];
  const float* g_l0b = (const float*)d_in[11];
  const float* b_l0b = (const float*)d_in[12];
  const float* w_l1a = (const float*)d_in[13];
  const float* g_l1a = (const float*)d_in[14];
  const float* b_l1a = (const float*)d_in[15];
  const float* w_l1b = (const float*)d_in[16];
  const float* g_l1b = (const float*)d_in[17];
  const float* b_l1b = (const float*)d_in[18];
  float* out = (float*)d_out;

  k_zero<<<48, 256, 0, stream>>>();

  // stage 1: xyz -> 64 -> 256 (f32)
  k_lin1<<<2048, 256, 0, stream>>>(xyz, w_c1);
  k_stats<<<1, 64, 0, stream>>>(g_c1, b_c1, 0, 1, 12, 13, 1.f / 8192.f);
  k_lin2<<<512, 256, 0, stream>>>(w_c2);
  k_stats<<<4, 64, 0, stream>>>(g_c2, b_c2, 2, 3, 14, 15, 1.f / 8192.f);
  k_bnrelu_h2<<<8192, 256, 0, stream>>>();

  // kNN shared by both spa_group calls: 1 wave/query
  k_knn<<<2048, 256, 0, stream>>>(xyz);

  // weight prep: stacked [W1 ; W2-W1] for F-GEMMs, plain for GEMM-b
  k_prep_wst<<<1024, 256, 0, stream>>>(w_l0a, 0, 8, 512, 262144);
  k_prep_w<<<1024, 256, 0, stream>>>(w_l0b, 1, 262144);
  k_prep_wst<<<4096, 256, 0, stream>>>(w_l1a, 2, 9, 1024, 1048576);
  k_prep_w<<<4096, 256, 0, stream>>>(w_l1b, 3, 1048576);

  // local_op 0: F[8192,1024] = h2b @ Wst^T (C=256), combine, bnrelu, pool-GEMM
  k_fgemm<<<128, 512, 0, stream>>>(0, 256, 1024, 2);
  k_combine<<<256, 512, 0, stream>>>(512, 6, 4, 5);
  k_stats<<<8, 64, 0, stream>>>(g_l0a, b_l0a, 4, 5, 16, 17, 1.f / 65536.f);
  k_bnrelu_z<<<2048, 256, 0, stream>>>(16, 17, 511, (size_t)65536 * 512 / 8);
  k_gp8<<<512, 512, 0, stream>>>(0, 512, 512, 6, 7, 1);
  k_stats<<<8, 64, 0, stream>>>(g_l0b, b_l0b, 6, 7, 18, 19, 1.f / 65536.f);
  k_bnrelu_pool<<<16384, 256, 0, stream>>>();

  // local_op 1: F[8192,2048] = hl0b @ Wst^T (C=512)
  k_fgemm<<<256, 512, 0, stream>>>(1, 512, 2048, 3);
  k_combine<<<256, 512, 0, stream>>>(1024, 7, 8, 9);
  k_stats<<<16, 64, 0, stream>>>(g_l1a, b_l1a, 8, 9, 20, 21, 1.f / 65536.f);
  k_bnrelu_z<<<2048, 256, 0, stream>>>(20, 21, 1023, (size_t)65536 * 1024 / 8);
  k_gp8<<<1024, 512, 0, stream>>>(1, 1024, 1024, 10, 11, 2);
  k_stats<<<16, 64, 0, stream>>>(g_l1b, b_l1b, 10, 11, 22, 23, 1.f / 65536.f);
  k_final_t<<<dim3(16, 32, 4), 256, 0, stream>>>(out);
}

// Round 8
// 737.412 us; speedup vs baseline: 1.7111x; 1.0488x over previous
//
#include <hip/hip_runtime.h>

typedef unsigned short u16;
typedef __attribute__((ext_vector_type(8))) short s16x8;
typedef __attribute__((ext_vector_type(8))) __bf16 bf16x8;
typedef __attribute__((ext_vector_type(8))) unsigned short u16x8;
typedef __attribute__((ext_vector_type(4))) float f32x4;

#define BN_EPS 1e-5f

// ---------- static device buffers (~219 MiB .bss; d_ws not used) ----------
__device__ u16   g_Z[(size_t)65536 * 1024];      // 128 MiB combined A for GEMM-b
__device__ u16   g_F[(size_t)8192 * 2048];       // 32 MiB  F = feat @ [W1 ; W2-W1]^T
__device__ float g_pooled[(size_t)8192 * 1024];  // 32 MiB pooled pre-BN
__device__ float g_h2pre[8192 * 256];            // 8 MiB
__device__ u16   g_h2b[8192 * 256];              // 4 MiB feat0 bf16
__device__ u16   g_hl0b[8192 * 512];             // 8 MiB feat1 bf16
__device__ float g_y1[8192 * 64];                // 2 MiB
__device__ u16   g_wm0a[1024 * 256];             // stacked [W1 ; W2-W1] l0
__device__ u16   g_w0b[512 * 512];
__device__ u16   g_wm1a[2048 * 512];             // stacked l1
__device__ u16   g_w1b[1024 * 1024];
__device__ int   g_nidx[65536];                  // global feat row of each neighbor
__device__ float g_st[24 * 1024];                // stats/scale/bias slots

#define S(i) (g_st + (i) * 1024)

static __device__ __forceinline__ float bf2f(u16 u) {
  unsigned int x = ((unsigned int)u) << 16;
  return __builtin_bit_cast(float, x);
}
static __device__ __forceinline__ u16 f2bf(float f) {
  unsigned int x = __builtin_bit_cast(unsigned int, f);
  x += 0x7fffu + ((x >> 16) & 1u);   // RNE
  return (u16)(x >> 16);
}
static __device__ __forceinline__ f32x4 mfma16x16(s16x8 a, s16x8 b, f32x4 c) {
  return __builtin_amdgcn_mfma_f32_16x16x32_bf16(
      __builtin_bit_cast(bf16x8, a), __builtin_bit_cast(bf16x8, b), c, 0, 0, 0);
}
static __device__ __forceinline__ void gl_lds16(const void* g, void* l) {
  __builtin_amdgcn_global_load_lds((const __attribute__((address_space(1))) void*)g,
                                   (__attribute__((address_space(3))) void*)l, 16, 0, 0);
}

// ---------------- zero stats accumulators ----------------
__global__ void k_zero() {
  int i = blockIdx.x * 256 + threadIdx.x;
  if (i < 12 * 1024) g_st[i] = 0.f;
}

// ---------------- stage 1a: y1[8192,64] = xyz @ w_c1^T, + channel sums ----------------
__global__ void k_lin1(const float* __restrict__ xyz, const float* __restrict__ w) {
  __shared__ float ls[64], lq[64];
  int t = threadIdx.x;
  if (t < 64) { ls[t] = 0.f; lq[t] = 0.f; }
  __syncthreads();
  int e = blockIdx.x * 256 + t;      // 8192*64, grid 2048
  int row = e >> 6, ch = e & 63;
  float x0 = xyz[row * 3], x1 = xyz[row * 3 + 1], x2 = xyz[row * 3 + 2];
  float v = x0 * w[ch * 3] + x1 * w[ch * 3 + 1] + x2 * w[ch * 3 + 2];
  g_y1[e] = v;
  atomicAdd(&ls[ch], v);
  atomicAdd(&lq[ch], v * v);
  __syncthreads();
  if (t < 64) { atomicAdd(&S(0)[t], ls[t]); atomicAdd(&S(1)[t], lq[t]); }
}

// ---------------- stats -> scale/bias ----------------
__global__ void k_stats(const float* __restrict__ g, const float* __restrict__ b,
                        int si_s, int si_q, int si_sc, int si_bi, float invcnt) {
  int c = blockIdx.x * 64 + threadIdx.x;
  float m = S(si_s)[c] * invcnt;
  float v = S(si_q)[c] * invcnt - m * m;
  float sc = g[c] * rsqrtf(v + BN_EPS);
  S(si_sc)[c] = sc;
  S(si_bi)[c] = b[c] - m * sc;
}

// ---------------- stage 1b: h2pre[8192,256] = relu(bn(y1)) @ w_c2^T ----------------
__global__ void k_lin2(const float* __restrict__ w) {
  __shared__ float hrow[64];
  int t = threadIdx.x;         // channel 0..255
  float wr[64];
#pragma unroll
  for (int i = 0; i < 64; i++) wr[i] = w[t * 64 + i];
  const float* sc1 = S(12);
  const float* bi1 = S(13);
  float ps = 0.f, pq = 0.f;
  int r0 = blockIdx.x * 16;    // grid 512
  for (int r = 0; r < 16; r++) {
    if (t < 64) {
      float v = g_y1[(r0 + r) * 64 + t];
      v = v * sc1[t] + bi1[t];
      hrow[t] = v > 0.f ? v : 0.f;
    }
    __syncthreads();
    float acc = 0.f;
#pragma unroll
    for (int i = 0; i < 64; i++) acc += hrow[i] * wr[i];
    g_h2pre[(r0 + r) * 256 + t] = acc;
    ps += acc;
    pq += acc * acc;
    __syncthreads();
  }
  atomicAdd(&S(2)[t], ps);
  atomicAdd(&S(3)[t], pq);
}

// ---------------- bn+relu f32 -> bf16 (h2pre -> h2b) ----------------
__global__ void k_bnrelu_h2() {
  int i = blockIdx.x * 256 + threadIdx.x;  // grid 8192
  if (i >= 8192 * 256) return;
  int c = i & 255;
  float v = g_h2pre[i] * S(14)[c] + S(15)[c];
  g_h2b[i] = f2bf(v > 0.f ? v : 0.f);
}

// ---------------- kNN (k=8), one WAVE per query ----------------
__global__ __launch_bounds__(256) void k_knn(const float* __restrict__ xyz) {
  int t = threadIdx.x, lane = t & 63, w = t >> 6;
  int qn = blockIdx.x * 4 + w;          // global query row 0..8191
  int b = qn >> 11;
  const float* xb = xyz + (size_t)b * 2048 * 3;
  int ql = qn & 2047;
  float qx = xb[ql * 3], qy = xb[ql * 3 + 1], qz = xb[ql * 3 + 2];
  float qsq = qx * qx + qy * qy + qz * qz;

  float bd[8];
  int bi[8];
#pragma unroll
  for (int i = 0; i < 8; i++) { bd[i] = 1e30f; bi[i] = 0x7fffffff; }

#pragma unroll 4
  for (int i = 0; i < 32; i++) {
    int j = lane + i * 64;
    float x = xb[j * 3], y = xb[j * 3 + 1], z = xb[j * 3 + 2];
    float sq = x * x + y * y + z * z;
    float d = qsq + sq - 2.0f * (qx * x + qy * y + qz * z);
    if (d < bd[7]) {
      bd[7] = d; bi[7] = j;
#pragma unroll
      for (int p = 7; p > 0; p--) {
        if (bd[p] < bd[p - 1]) {
          float td = bd[p]; bd[p] = bd[p - 1]; bd[p - 1] = td;
          int ti = bi[p]; bi[p] = bi[p - 1]; bi[p - 1] = ti;
        }
      }
    }
  }

  // 8-round wave merge: pop global (d, idx)-min each round.
  int keep = 0;
#pragma unroll
  for (int r = 0; r < 8; r++) {
    float md = bd[0];
    int mi = bi[0];
#pragma unroll
    for (int s = 1; s < 64; s <<= 1) {
      float od = __shfl_xor(md, s, 64);
      int oi = __shfl_xor(mi, s, 64);
      if (od < md || (od == md && oi < mi)) { md = od; mi = oi; }
    }
    bool own = (bd[0] == md) && (bi[0] == mi);
    if (own) {
#pragma unroll
      for (int p = 0; p < 7; p++) { bd[p] = bd[p + 1]; bi[p] = bi[p + 1]; }
      bd[7] = 1e30f; bi[7] = 0x7fffffff;
    }
    if (lane == r) keep = mi;
  }
  if (lane < 8) g_nidx[qn * 8 + lane] = b * 2048 + keep;
}

// ------- plain weight bf16 prep: which 1=w0b 3=w1b -------
__global__ void k_prep_w(const float* __restrict__ src, int which, int n) {
  int i = blockIdx.x * 256 + threadIdx.x;
  if (i >= n) return;
  u16* dst = which == 1 ? g_w0b : g_w1b;
  dst[i] = f2bf(src[i]);
}

// ------- stacked weight prep: Wst[2N, C]: rows [0,N)=W1, [N,2N)=W2-W1 -------
__global__ void k_prep_wst(const float* __restrict__ src, int which, int lc, int N, int n) {
  int i = blockIdx.x * 256 + threadIdx.x;
  if (i >= n) return;
  int C = 1 << lc;
  int r = i >> lc, c = i & (C - 1);
  float v;
  if (r < N) v = src[r * 2 * C + c];
  else { int o = r - N; v = src[o * 2 * C + C + c] - src[o * 2 * C + c]; }
  u16* dst = which == 0 ? g_wm0a : g_wm1a;
  dst[i] = f2bf(v);
}

// ============ 256x256-tile BK=64 8-phase GEMM core (T2+T3+T4+T5) ============
// 512 thr = 8 waves (2M x 4N); per-wave 128x64; acc[8][4] f32x4.
// LDS: 2 K-tile dbuf x (A 32KB + B 32KB) = 128KB, in 4 x 8KB strips per tensor.
// XOR swizzle: phys_chunk = log_chunk ^ (row&7) (inverse-swz global src, swz ds_read).
// Per K-tile: 4 quadrant phases {stage half-tiles of kt+2 | ds_read | barrier |
// lgkmcnt(0) | setprio(1) 16xMFMA setprio(0) | barrier}; staging of a region is
// issued only in the phase AFTER the barrier retiring its last LDS read:
//   p1: A rows {0-63,128-191}  (last read p0)
//   p2: B all                  (last read p1)
//   p3: A rows {64-127,192-255}(last read p2)
// vmcnt(6) once per tile (end of p3) drains exactly tile kt+1's 8 loads.

#define BARRIER_F() { __builtin_amdgcn_s_barrier(); asm volatile("" ::: "memory"); }

#define GEMM8_PRO()                                                       \
  int t = threadIdx.x, lane = t & 63, w = t >> 6;                         \
  int chunk = gridDim.x >> 3;                                             \
  int idx = ((int)blockIdx.x & 7) * chunk + ((int)blockIdx.x >> 3);       \
  int bx = idx & ((1 << lbx) - 1), by = idx >> lbx;                       \
  int wm = w >> 2, wn = w & 3;                                            \
  int l15 = lane & 15, lq = lane >> 4;                                    \
  int c0 = lq ^ (l15 & 7);                                                \
  int ab0 = wm * 8192 + l15 * 64 + c0 * 8;                                \
  int ab1 = wm * 8192 + l15 * 64 + (c0 ^ 4) * 8;                          \
  int bb0 = (wn >> 1) * 8192 + (wn & 1) * 4096 + l15 * 64 + c0 * 8;       \
  int bb1 = (wn >> 1) * 8192 + (wn & 1) * 4096 + l15 * 64 + (c0 ^ 4) * 8; \
  int sr = t >> 3, skc = (t & 7) ^ ((t >> 3) & 7);                        \
  f32x4 acc[8][4];                                                        \
  _Pragma("unroll") for (int m = 0; m < 8; m++)                           \
  _Pragma("unroll") for (int n = 0; n < 4; n++)                           \
      acc[m][n] = f32x4{0.f, 0.f, 0.f, 0.f};

#define GEMM8_LOOP(Ag, Bg)                                                    \
  const u16* a0 = (Ag) + (size_t)(by * 256 + sr) * K + skc * 8;               \
  const u16* b0 = (Bg) + (size_t)(bx * 256 + sr) * K + skc * 8;               \
  _Pragma("unroll") for (int tl = 0; tl < 2; tl++) {                          \
    u16* AW = As + tl * 16384; u16* BW = Bs + tl * 16384;                     \
    int cc = tl * 64;                                                         \
    gl_lds16(a0 + cc, AW + t * 8);                                            \
    gl_lds16(a0 + (size_t)128 * K + cc, AW + 8192 + t * 8);                   \
    gl_lds16(a0 + (size_t)64 * K + cc, AW + 4096 + t * 8);                    \
    gl_lds16(a0 + (size_t)192 * K + cc, AW + 12288 + t * 8);                  \
    gl_lds16(b0 + cc, BW + t * 8);                                            \
    gl_lds16(b0 + (size_t)64 * K + cc, BW + 4096 + t * 8);                    \
    gl_lds16(b0 + (size_t)128 * K + cc, BW + 8192 + t * 8);                   \
    gl_lds16(b0 + (size_t)192 * K + cc, BW + 12288 + t * 8);                  \
  }                                                                           \
  asm volatile("s_waitcnt vmcnt(8)" ::: "memory");                            \
  BARRIER_F();                                                                \
  for (int kt = 0; kt < nk; kt++) {                                           \
    u16* AsR = As + (kt & 1) * 16384;                                         \
    u16* BsR = Bs + (kt & 1) * 16384;                                         \
    bool st = (kt + 2 < nk);                                                  \
    int c2 = (kt + 2) * 64;                                                   \
    s16x8 af[8], bfl[4], bfh[4];                                              \
    /* ---- phase 0: quadrant (0,0) ---- */                                   \
    _Pragma("unroll") for (int ks = 0; ks < 2; ks++)                          \
    _Pragma("unroll") for (int m = 0; m < 4; m++)                             \
        af[ks * 4 + m] = *(const s16x8*)&AsR[(ks ? ab1 : ab0) + m * 1024];    \
    _Pragma("unroll") for (int ks = 0; ks < 2; ks++)                          \
    _Pragma("unroll") for (int n = 0; n < 2; n++)                             \
        bfl[ks * 2 + n] = *(const s16x8*)&BsR[(ks ? bb1 : bb0) + n * 1024];   \
    BARRIER_F();                                                              \
    asm volatile("s_waitcnt lgkmcnt(0)" ::: "memory");                        \
    __builtin_amdgcn_sched_barrier(0);                                        \
    __builtin_amdgcn_s_setprio(1);                                            \
    _Pragma("unroll") for (int ks = 0; ks < 2; ks++)                          \
    _Pragma("unroll") for (int m = 0; m < 4; m++)                             \
    _Pragma("unroll") for (int n = 0; n < 2; n++)                             \
        acc[m][n] = mfma16x16(af[ks * 4 + m], bfl[ks * 2 + n], acc[m][n]);    \
    __builtin_amdgcn_s_setprio(0);                                            \
    BARRIER_F();                                                              \
    /* ---- phase 1: quadrant (0,1); stage A strips {0,128} of kt+2 ---- */   \
    if (st) {                                                                 \
      gl_lds16(a0 + c2, AsR + t * 8);                                         \
      gl_lds16(a0 + (size_t)128 * K + c2, AsR + 8192 + t * 8);                \
    }                                                                         \
    _Pragma("unroll") for (int ks = 0; ks < 2; ks++)                          \
    _Pragma("unroll") for (int n = 0; n < 2; n++)                             \
        bfh[ks * 2 + n] = *(const s16x8*)&BsR[(ks ? bb1 : bb0) + 2048 + n * 1024]; \
    BARRIER_F();                                                              \
    asm volatile("s_waitcnt lgkmcnt(0)" ::: "memory");                        \
    __builtin_amdgcn_sched_barrier(0);                                        \
    __builtin_amdgcn_s_setprio(1);                                            \
    _Pragma("unroll") for (int ks = 0; ks < 2; ks++)                          \
    _Pragma("unroll") for (int m = 0; m < 4; m++)                             \
    _Pragma("unroll") for (int n = 0; n < 2; n++)                             \
        acc[m][2 + n] = mfma16x16(af[ks * 4 + m], bfh[ks * 2 + n], acc[m][2 + n]); \
    __builtin_amdgcn_s_setprio(0);                                            \
    BARRIER_F();                                                              \
    /* ---- phase 2: quadrant (1,0); stage B of kt+2 ---- */                  \
    if (st) {                                                                 \
      gl_lds16(b0 + c2, BsR + t * 8);                                         \
      gl_lds16(b0 + (size_t)64 * K + c2, BsR + 4096 + t * 8);                 \
      gl_lds16(b0 + (size_t)128 * K + c2, BsR + 8192 + t * 8);                \
      gl_lds16(b0 + (size_t)192 * K + c2, BsR + 12288 + t * 8);               \
    }                                                                         \
    _Pragma("unroll") for (int ks = 0; ks < 2; ks++)                          \
    _Pragma("unroll") for (int m = 0; m < 4; m++)                             \
        af[ks * 4 + m] = *(const s16x8*)&AsR[(ks ? ab1 : ab0) + 4096 + m * 1024]; \
    BARRIER_F();                                                              \
    asm volatile("s_waitcnt lgkmcnt(0)" ::: "memory");                        \
    __builtin_amdgcn_sched_barrier(0);                                        \
    __builtin_amdgcn_s_setprio(1);                                            \
    _Pragma("unroll") for (int ks = 0; ks < 2; ks++)                          \
    _Pragma("unroll") for (int m = 0; m < 4; m++)                             \
    _Pragma("unroll") for (int n = 0; n < 2; n++)                             \
        acc[4 + m][n] = mfma16x16(af[ks * 4 + m], bfl[ks * 2 + n], acc[4 + m][n]); \
    __builtin_amdgcn_s_setprio(0);                                            \
    BARRIER_F();                                                              \
    /* ---- phase 3: quadrant (1,1); stage A strips {64,192} of kt+2 ---- */  \
    if (st) {                                                                 \
      gl_lds16(a0 + (size_t)64 * K + c2, AsR + 4096 + t * 8);                 \
      gl_lds16(a0 + (size_t)192 * K + c2, AsR + 12288 + t * 8);               \
    }                                                                         \
    __builtin_amdgcn_s_setprio(1);                                            \
    _Pragma("unroll") for (int ks = 0; ks < 2; ks++)                          \
    _Pragma("unroll") for (int m = 0; m < 4; m++)                             \
    _Pragma("unroll") for (int n = 0; n < 2; n++)                             \
        acc[4 + m][2 + n] = mfma16x16(af[ks * 4 + m], bfh[ks * 2 + n], acc[4 + m][2 + n]); \
    __builtin_amdgcn_s_setprio(0);                                            \
    if (kt < nk - 2) { asm volatile("s_waitcnt vmcnt(6)" ::: "memory"); }     \
    else             { asm volatile("s_waitcnt vmcnt(0)" ::: "memory"); }     \
    BARRIER_F();                                                              \
  }

#define GEMM_STATS(si_s, si_q)                                           \
  if (t < 256) { cs[t] = 0.f; cq[t] = 0.f; }                             \
  __syncthreads();                                                       \
  _Pragma("unroll") for (int n = 0; n < 4; n++) {                        \
    float ssum = 0.f, ssq = 0.f;                                         \
    _Pragma("unroll") for (int m = 0; m < 8; m++)                        \
    _Pragma("unroll") for (int j = 0; j < 4; j++) {                      \
      float v = acc[m][n][j];                                            \
      ssum += v;                                                         \
      ssq += v * v;                                                      \
    }                                                                    \
    int col = wn * 64 + n * 16 + l15;                                    \
    atomicAdd(&cs[col], ssum);                                           \
    atomicAdd(&cq[col], ssq);                                            \
  }                                                                      \
  __syncthreads();                                                       \
  if (t < 256) {                                                         \
    atomicAdd(&S(si_s)[bx * 256 + t], cs[t]);                            \
    atomicAdd(&S(si_q)[bx * 256 + t], cq[t]);                            \
  }

// ---- F-GEMM: F[8192, N2] = feat[8192, C] @ Wst[N2, C]^T (no stats) ----
__global__ __launch_bounds__(512) void k_fgemm(int layer, int C, int N2, int lbx) {
  __shared__ u16 As[2 * 16384];
  __shared__ u16 Bs[2 * 16384];
  const u16* feat = layer == 0 ? g_h2b : g_hl0b;
  const u16* W = layer == 0 ? g_wm0a : g_wm1a;
  int K = C, nk = C >> 6;
  GEMM8_PRO();
  GEMM8_LOOP(feat, W)

#pragma unroll
  for (int m = 0; m < 8; m++) {
    int rbase = by * 256 + wm * 128 + m * 16 + lq * 4;
#pragma unroll
    for (int n = 0; n < 4; n++) {
      int col = bx * 256 + wn * 64 + n * 16 + l15;
#pragma unroll
      for (int j = 0; j < 4; j++)
        g_F[(size_t)(rbase + j) * N2 + col] = f2bf(acc[m][n][j]);
    }
  }
}

// ---- combine: Z[row,c] = F[nidx[row], c] + F[row>>3, N+c]; + channel stats ----
__global__ __launch_bounds__(512) void k_combine(int N, int lgc, int si_s, int si_q) {
  __shared__ float Ls[1024], Lq[1024];
  int t = threadIdx.x;
  int chs8 = 1 << lgc;               // threads per row-slice (N/8)
  int c8 = t & (chs8 - 1);
  int g = t >> lgc;
  int G = 512 >> lgc;                // row groups per block
  int rpg = 256 / G;
  int row0 = blockIdx.x * 256 + g * rpg;
  int ch0 = c8 * 8;
  int N2 = 2 * N;
  float ss[8], sq[8];
#pragma unroll
  for (int j = 0; j < 8; j++) { ss[j] = 0.f; sq[j] = 0.f; }

  for (int r = row0; r < row0 + rpg; r++) {
    int nb = g_nidx[r];
    int ct = r >> 3;
    u16x8 a = *(const u16x8*)(g_F + (size_t)nb * N2 + ch0);
    u16x8 b = *(const u16x8*)(g_F + (size_t)ct * N2 + N + ch0);
    u16x8 o;
#pragma unroll
    for (int j = 0; j < 8; j++) {
      float z = bf2f(a[j]) + bf2f(b[j]);
      o[j] = f2bf(z);
      ss[j] += z;
      sq[j] += z * z;
    }
    *(u16x8*)(g_Z + (size_t)r * N + ch0) = o;
  }

  for (int c = t; c < N; c += 512) { Ls[c] = 0.f; Lq[c] = 0.f; }
  __syncthreads();
#pragma unroll
  for (int j = 0; j < 8; j++) {
    atomicAdd(&Ls[ch0 + j], ss[j]);
    atomicAdd(&Lq[ch0 + j], sq[j]);
  }
  __syncthreads();
  for (int c = t; c < N; c += 512) {
    atomicAdd(&S(si_s)[c], Ls[c]);
    atomicAdd(&S(si_q)[c], Lq[c]);
  }
}

// ---- pool GEMM: A=g_Z, epilogue max over k=8 -> g_pooled[8192,N] + stats ----
__global__ __launch_bounds__(512) void k_gp8(int layer, int Kp, int N, int si_s,
                                             int si_q, int lbx) {
  __shared__ u16 As[2 * 16384];
  __shared__ u16 Bs[2 * 16384];
  __shared__ float cs[256], cq[256];
  const u16* W = layer == 0 ? g_w0b : g_w1b;
  int K = Kp, nk = Kp >> 6;
  GEMM8_PRO();
  GEMM8_LOOP(g_Z, W)

  // max over k=8: frag rows m*16 + lq*4 + j; pair lq 0<->1, 2<->3 via lane^16
#pragma unroll
  for (int m = 0; m < 8; m++) {
    int prow = by * 32 + wm * 16 + m * 2 + (lq >> 1);
#pragma unroll
    for (int n = 0; n < 4; n++) {
      float v4 = fmaxf(fmaxf(acc[m][n][0], acc[m][n][1]), fmaxf(acc[m][n][2], acc[m][n][3]));
      float v8 = fmaxf(v4, __shfl_xor(v4, 16, 64));
      if ((lane & 16) == 0) {
        int col = bx * 256 + wn * 64 + n * 16 + l15;
        g_pooled[(size_t)prow * N + col] = v8;
      }
    }
  }
  GEMM_STATS(si_s, si_q)
}

// ---------------- in-place bn+relu on bf16 Z ----------------
__global__ void k_bnrelu_z(int si_sc, int si_bi, int cmask, size_t n8) {
  size_t i = (size_t)blockIdx.x * 256 + threadIdx.x;
  size_t stride = (size_t)gridDim.x * 256;
  const float* sc = S(si_sc);
  const float* bi = S(si_bi);
  for (; i < n8; i += stride) {
    u16x8 v = *(const u16x8*)(g_Z + i * 8);
    int c0 = (int)((i * 8) & (size_t)cmask);
    u16x8 o;
#pragma unroll
    for (int j = 0; j < 8; j++) {
      float f = bf2f(v[j]) * sc[c0 + j] + bi[c0 + j];
      o[j] = f2bf(f > 0.f ? f : 0.f);
    }
    *(u16x8*)(g_Z + i * 8) = o;
  }
}

// ---------------- bn+relu pooled f32 -> bf16 feat (local_op 0 only) ----------------
__global__ void k_bnrelu_pool() {
  int i = blockIdx.x * 256 + threadIdx.x;  // grid 16384, n = 8192*512
  if (i >= 8192 * 512) return;
  int c = i & 511;
  float v = g_pooled[i] * S(18)[c] + S(19)[c];
  g_hl0b[i] = f2bf(v > 0.f ? v : 0.f);
}

// ---------------- final: bn+relu pooled[8192,1024] -> out (B,1024,2048) f32 ----------------
__global__ void k_final_t(float* __restrict__ out) {
  __shared__ float tile[64][65];
  int b = blockIdx.z;     // 4
  int nb = blockIdx.y;    // 32
  int cb = blockIdx.x;    // 16
  int t = threadIdx.x;
  int cl = t & 63;
  int c = cb * 64 + cl;
  float sc = S(22)[c], bi = S(23)[c];
  for (int nl = t >> 6; nl < 64; nl += 4) {
    float v = g_pooled[(size_t)(b * 2048 + nb * 64 + nl) * 1024 + c] * sc + bi;
    tile[nl][cl] = v > 0.f ? v : 0.f;
  }
  __syncthreads();
  int nl2 = t & 63;
  for (int ci = t >> 6; ci < 64; ci += 4) {
    out[((size_t)b * 1024 + cb * 64 + ci) * 2048 + nb * 64 + nl2] = tile[nl2][ci];
  }
}

extern "C" void kernel_launch(void* const* d_in, const int* in_sizes, int n_in,
                              void* d_out, int out_size, void* d_ws, size_t ws_size,
                              hipStream_t stream) {
  const float* xyz  = (const float*)d_in[0];
  const float* w_c1 = (const float*)d_in[1];
  const float* g_c1 = (const float*)d_in[2];
  const float* b_c1 = (const float*)d_in[3];
  const float* w_c2 = (const float*)d_in[4];
  const float* g_c2 = (const float*)d_in[5];
  const float* b_c2 = (const float*)d_in[6];
  const float* w_l0a = (const float*)d_in[7];
  const float* g_l0a = (const float*)d_in[8];
  const float* b_l0a = (const float*)d_in[9];
  const float* w_l0b = (const float*)d_in[10];
  const float* g_l0b = (const float*)d_in[11];
  const float* b_l0b = (const float*)d_in[12];
  const float* w_l1a = (const float*)d_in[13];
  const float* g_l1a = (const float*)d_in[14];
  const float* b_l1a = (const float*)d_in[15];
  const float* w_l1b = (const float*)d_in[16];
  const float* g_l1b = (const float*)d_in[17];
  const float* b_l1b = (const float*)d_in[18];
  float* out = (float*)d_out;

  k_zero<<<48, 256, 0, stream>>>();

  // stage 1: xyz -> 64 -> 256 (f32)
  k_lin1<<<2048, 256, 0, stream>>>(xyz, w_c1);
  k_stats<<<1, 64, 0, stream>>>(g_c1, b_c1, 0, 1, 12, 13, 1.f / 8192.f);
  k_lin2<<<512, 256, 0, stream>>>(w_c2);
  k_stats<<<4, 64, 0, stream>>>(g_c2, b_c2, 2, 3, 14, 15, 1.f / 8192.f);
  k_bnrelu_h2<<<8192, 256, 0, stream>>>();

  // kNN shared by both spa_group calls: 1 wave/query
  k_knn<<<2048, 256, 0, stream>>>(xyz);

  // weight prep: stacked [W1 ; W2-W1] for F-GEMMs, plain for GEMM-b
  k_prep_wst<<<1024, 256, 0, stream>>>(w_l0a, 0, 8, 512, 262144);
  k_prep_w<<<1024, 256, 0, stream>>>(w_l0b, 1, 262144);
  k_prep_wst<<<4096, 256, 0, stream>>>(w_l1a, 2, 9, 1024, 1048576);
  k_prep_w<<<4096, 256, 0, stream>>>(w_l1b, 3, 1048576);

  // local_op 0: F[8192,1024] = h2b @ Wst^T (C=256), combine, bnrelu, pool-GEMM
  k_fgemm<<<128, 512, 0, stream>>>(0, 256, 1024, 2);
  k_combine<<<256, 512, 0, stream>>>(512, 6, 4, 5);
  k_stats<<<8, 64, 0, stream>>>(g_l0a, b_l0a, 4, 5, 16, 17, 1.f / 65536.f);
  k_bnrelu_z<<<2048, 256, 0, stream>>>(16, 17, 511, (size_t)65536 * 512 / 8);
  k_gp8<<<512, 512, 0, stream>>>(0, 512, 512, 6, 7, 1);
  k_stats<<<8, 64, 0, stream>>>(g_l0b, b_l0b, 6, 7, 18, 19, 1.f / 65536.f);
  k_bnrelu_pool<<<16384, 256, 0, stream>>>();

  // local_op 1: F[8192,2048] = hl0b @ Wst^T (C=512)
  k_fgemm<<<256, 512, 0, stream>>>(1, 512, 2048, 3);
  k_combine<<<256, 512, 0, stream>>>(1024, 7, 8, 9);
  k_stats<<<16, 64, 0, stream>>>(g_l1a, b_l1a, 8, 9, 20, 21, 1.f / 65536.f);
  k_bnrelu_z<<<2048, 256, 0, stream>>>(20, 21, 1023, (size_t)65536 * 1024 / 8);
  k_gp8<<<1024, 512, 0, stream>>>(1, 1024, 1024, 10, 11, 2);
  k_stats<<<16, 64, 0, stream>>>(g_l1b, b_l1b, 10, 11, 22, 23, 1.f / 65536.f);
  k_final_t<<<dim3(16, 32, 4), 256, 0, stream>>>(out);
}